// Round 9
// baseline (312.501 us; speedup 1.0000x reference)
//
#include <hip/hip_runtime.h>

#define BATCH 16
#define NPTS 1024
#define CIN 16
#define NODES (BATCH*NPTS)      // 16384
#define KNN 10
#define EDGES (NODES*KNN)       // 163840
#define JCH 16                  // j-chunks for KNN
#define JLEN (NPTS/JCH)         // 64

typedef unsigned short ushort_t;
typedef __attribute__((ext_vector_type(8))) short bf16x8;
typedef __attribute__((ext_vector_type(8))) unsigned short u16x8;
typedef __attribute__((ext_vector_type(4))) float f32x4;
typedef __attribute__((ext_vector_type(2))) float f32x2;

__device__ __forceinline__ int uclamp(int v, int hi) {
    return ((unsigned)v > (unsigned)hi) ? hi : v;
}
__device__ __forceinline__ float bf2f(ushort_t u) {
    union { unsigned int i; float f; } v; v.i = ((unsigned int)u) << 16; return v.f;
}
__device__ __forceinline__ ushort_t f2bf(float f) {
    union { float f; unsigned int i; } v; v.f = f;
    unsigned int r = (v.i + 0x7fffu + ((v.i >> 16) & 1u)) >> 16;
    return (ushort_t)r;
}

// ---------------- cast layer-1..3 weights f32 -> bf16 (229376 elems) ----------------
__global__ __launch_bounds__(256) void cast_weights(const float* __restrict__ s0,
                                                    const float* __restrict__ s1,
                                                    const float* __restrict__ s2,
                                                    const float* __restrict__ s3,
                                                    const float* __restrict__ s4,
                                                    const float* __restrict__ s5,
                                                    ushort_t* __restrict__ dst,
                                                    const float* __restrict__ xf,
                                                    float* __restrict__ sqh,
                                                    int* __restrict__ cntz) {
    int t = blockIdx.x * 256 + threadIdx.x;   // 896 blocks
    if (t < NODES) {
        const float4* xp = (const float4*)(xf + (size_t)t * 16);
        float4 a = xp[0], b = xp[1], c = xp[2], d = xp[3];
        float s = a.x*a.x + a.y*a.y + a.z*a.z + a.w*a.w
                + b.x*b.x + b.y*b.y + b.z*b.z + b.w*b.w
                + c.x*c.x + c.y*c.y + c.z*c.z + c.w*c.w
                + d.x*d.x + d.y*d.y + d.z*d.z + d.w*d.w;
        sqh[t] = 0.5f * s;
    }
    if (t < 2 * NODES) cntz[t] = 0;           // cnt (16384) + cur (16384), contiguous
    const float* s; int off;
    if      (t <  32768) { s = s0; off = 0; }
    else if (t <  65536) { s = s1; off = 32768; }
    else if (t < 131072) { s = s2; off = 65536; }
    else if (t < 196608) { s = s3; off = 131072; }
    else if (t < 212992) { s = s4; off = 196608; }
    else                 { s = s5; off = 212992; }
    dst[t] = f2bf(s[t - off]);
}

// ---------------- KNN phase A: per-(i, j-chunk) top-10 ----------------
// grid dim3(JCH=16, 8, BATCH) = 2048 blocks (8/CU -> 16 waves/CU), 128 threads.
__global__ __launch_bounds__(128, 4) void knn_partial(const float* __restrict__ xf,
                                                      const float* __restrict__ sqh,
                                                      float* __restrict__ pd,
                                                      ushort_t* __restrict__ pi_) {
    int jc = blockIdx.x, ic = blockIdx.y, b = blockIdx.z;
    int tid = threadIdx.x;                    // 0..127
    int i_local = (ic << 7) | tid;
    const float* xbp = xf + (size_t)b * NPTS * CIN;
    const float* sqb = sqh + b * NPTS;

    f32x2 nxi[8];
    {
        const f32x2* xip = (const f32x2*)(xbp + (size_t)i_local * 16);
#pragma unroll
        for (int q = 0; q < 8; ++q) nxi[q] = -xip[q];
    }

    int jbase = jc * JLEN;
    const float* yb = xbp + (size_t)jbase * 16;   // wave-uniform base

    float bd[10]; int bi[10];
#pragma unroll
    for (int r = 0; r < 10; ++r) { bd[r] = 3.0e38f; bi[r] = 0; }

#pragma unroll 4
    for (int jl = 0; jl < JLEN; ++jl) {
        const f32x2* y2 = (const f32x2*)(yb + jl * 16);   // uniform -> s_load
        f32x2 acc2 = {sqb[jbase + jl], 0.0f};             // uniform scalar seed
#pragma unroll
        for (int d = 0; d < 8; ++d) acc2 = __builtin_elementwise_fma(nxi[d], y2[d], acc2);
        float dist = acc2.x + acc2.y;
        int j = jbase + jl;
        float c = (j != i_local) ? dist : 3.0e38f;
        bool m[10];
#pragma unroll
        for (int k = 0; k < 10; ++k) m[k] = c < bd[k];
#pragma unroll
        for (int k = 9; k >= 1; --k) {
            int t = m[k-1] ? bi[k-1] : j;
            bi[k] = m[k] ? t : bi[k];
            bd[k] = __builtin_amdgcn_fmed3f(c, bd[k-1], bd[k]);
        }
        bi[0] = m[0] ? j : bi[0];
        bd[0] = fminf(c, bd[0]);
    }
    size_t base = ((size_t)(b * NPTS + i_local) * JCH + jc) * 10;
#pragma unroll
    for (int r = 0; r < 10; ++r) { pd[base + r] = bd[r]; pi_[base + r] = (ushort_t)bi[r]; }
}

// ---------------- KNN phase B: lane-parallel merge, 16 lanes per node ----------------
// 1024 blocks x 256 threads; lane l of a 16-lane group owns sorted list jc=l.
__global__ __launch_bounds__(256) void knn_merge(const float* __restrict__ pd,
                                                 const ushort_t* __restrict__ pi_,
                                                 int* __restrict__ nbors,
                                                 int* __restrict__ cnt) {
    int tid = blockIdx.x * 256 + threadIdx.x;     // 0..262143
    int node = tid >> 4;                          // 0..16383
    int sub  = tid & 15;                          // list index (jc)
    int b = node >> 10, i = node & 1023;
    int lane = threadIdx.x & 63;

    size_t base = ((size_t)node * JCH + sub) * 10;
    float d[11]; int id[10];
    {
        const float2* dp = (const float2*)(pd + base);
        const unsigned int* ip = (const unsigned int*)(pi_ + base);
#pragma unroll
        for (int q = 0; q < 5; ++q) {
            float2 dv = dp[q];
            unsigned int iv = ip[q];
            d[2*q] = dv.x; d[2*q+1] = dv.y;
            id[2*q] = (int)(iv & 0xffffu); id[2*q+1] = (int)(iv >> 16);
        }
        d[10] = 3.0e38f;
    }

    int res[10];
#pragma unroll
    for (int r = 0; r < 10; ++r) {
        float hd = d[0]; int hl = sub;
#pragma unroll
        for (int mk = 1; mk <= 8; mk <<= 1) {
            float od = __shfl_xor(hd, mk, 64);
            int   ol = __shfl_xor(hl, mk, 64);
            bool take = (od < hd) || (od == hd && ol < hl);
            hd = take ? od : hd;
            hl = take ? ol : hl;
        }
        int src = (lane & 48) | hl;
        res[r] = __shfl(id[0], src, 64);
        bool win = (sub == hl);
#pragma unroll
        for (int k = 0; k < 9; ++k) {
            d[k]  = win ? d[k+1]  : d[k];
            id[k] = win ? id[k+1] : id[k];
        }
        d[9] = win ? d[10] : d[9];
    }

    if (sub == 0) {
        int gi = b * NPTS + i;
#pragma unroll
        for (int r = 0; r < 10; ++r) {
            int gdst = b * NPTS + uclamp(res[r], NPTS - 1);
            nbors[gi * KNN + r] = gdst;
            atomicAdd(&cnt[gdst], 1);
        }
    }
}

// ---------------- reverse-CSR build ----------------
__global__ __launch_bounds__(256) void scan_kernel(const int* __restrict__ cnt,
                                                   int* __restrict__ rs) {
    __shared__ int part[256];
    int t = threadIdx.x;
    int base = t << 6;
    int4 v[16];
    const int4* cp = (const int4*)(cnt + base);
#pragma unroll
    for (int q = 0; q < 16; ++q) v[q] = cp[q];
    int s = 0;
#pragma unroll
    for (int q = 0; q < 16; ++q) s += v[q].x + v[q].y + v[q].z + v[q].w;
    part[t] = s;
    __syncthreads();
    for (int off = 1; off < 256; off <<= 1) {
        int vv = (t >= off) ? part[t - off] : 0;
        __syncthreads();
        part[t] += vv;
        __syncthreads();
    }
    int run = part[t] - s;
    int4* rp = (int4*)(rs + base);
#pragma unroll
    for (int q = 0; q < 16; ++q) {
        int4 o;
        o.x = run; run += v[q].x;
        o.y = run; run += v[q].y;
        o.z = run; run += v[q].z;
        o.w = run; run += v[q].w;
        rp[q] = o;
    }
    if (t == 255) rs[NODES] = run;
}

__global__ __launch_bounds__(256) void fill_kernel(const int* __restrict__ nbors,
                                                   const int* __restrict__ rs,
                                                   int* __restrict__ cur,
                                                   int* __restrict__ esrc) {
    int e = blockIdx.x * 256 + threadIdx.x;
    if (e < EDGES) {
        int dst = uclamp(nbors[e], NODES - 1);
        int src = e / 10;
        int pos = atomicAdd(&cur[dst], 1);
        esrc[uclamp(rs[dst] + pos, EDGES - 1)] = src;
    }
}

// ---------------- layer-0 GEMM (f32 vector, K=16, N=128) + fused neighbor-agg -------
// grid 256 blocks x 256: block = 64 rows x all 128 cols (no gather duplication).
__global__ __launch_bounds__(256) void gemm_layer0(const float* __restrict__ A1,
                                                   const int* __restrict__ rs,
                                                   const int* __restrict__ esrc,
                                                   const float* __restrict__ W1,
                                                   const float* __restrict__ W2,
                                                   const float* __restrict__ bias,
                                                   ushort_t* __restrict__ Out) {
    __shared__ float As1[16 * 64], As2[16 * 64], Bs1[16 * 128], Bs2[16 * 128];
    int tid = threadIdx.x;
    int m0 = blockIdx.x * 64;

    {   // stage x^T for this block's 64 rows
        int lr = tid >> 2, lc = (tid & 3) << 2;
        float4 a = *(const float4*)(A1 + (size_t)(m0 + lr) * 16 + lc);
        As1[(lc + 0) * 64 + lr] = a.x; As1[(lc + 1) * 64 + lr] = a.y;
        As1[(lc + 2) * 64 + lr] = a.z; As1[(lc + 3) * 64 + lr] = a.w;
    }
    {   // stage both weight matrices (128 x 16) transposed
        int wr = tid >> 1, wc = (tid & 1) << 3;
        float4 wa = *(const float4*)(W1 + (size_t)wr * 16 + wc);
        float4 wb = *(const float4*)(W1 + (size_t)wr * 16 + wc + 4);
        Bs1[(wc + 0) * 128 + wr] = wa.x; Bs1[(wc + 1) * 128 + wr] = wa.y;
        Bs1[(wc + 2) * 128 + wr] = wa.z; Bs1[(wc + 3) * 128 + wr] = wa.w;
        Bs1[(wc + 4) * 128 + wr] = wb.x; Bs1[(wc + 5) * 128 + wr] = wb.y;
        Bs1[(wc + 6) * 128 + wr] = wb.z; Bs1[(wc + 7) * 128 + wr] = wb.w;
        float4 va = *(const float4*)(W2 + (size_t)wr * 16 + wc);
        float4 vb = *(const float4*)(W2 + (size_t)wr * 16 + wc + 4);
        Bs2[(wc + 0) * 128 + wr] = va.x; Bs2[(wc + 1) * 128 + wr] = va.y;
        Bs2[(wc + 2) * 128 + wr] = va.z; Bs2[(wc + 3) * 128 + wr] = va.w;
        Bs2[(wc + 4) * 128 + wr] = vb.x; Bs2[(wc + 5) * 128 + wr] = vb.y;
        Bs2[(wc + 6) * 128 + wr] = vb.z; Bs2[(wc + 7) * 128 + wr] = vb.w;
    }
    {   // fused agg: 4 threads per row, 4 channels each
        int r = tid >> 2;
        int c4 = (tid & 3) << 2;
        int n = m0 + r;
        int e1 = uclamp(rs[n + 1], EDGES);
        int e0 = uclamp(rs[n], e1);
        float4 acc4 = {0.f, 0.f, 0.f, 0.f};
        for (int e = e0; e < e1; ++e) {
            int s = uclamp(esrc[e], NODES - 1);
            float4 v = *(const float4*)(A1 + (size_t)s * 16 + c4);
            acc4.x += v.x; acc4.y += v.y; acc4.z += v.z; acc4.w += v.w;
        }
        As2[(c4 + 0) * 64 + r] = acc4.x; As2[(c4 + 1) * 64 + r] = acc4.y;
        As2[(c4 + 2) * 64 + r] = acc4.z; As2[(c4 + 3) * 64 + r] = acc4.w;
    }
    __syncthreads();

    float acc[4][8] = {};
    int ty = tid >> 4;     // 16 row-groups of 4 -> 64 rows
    int tx = tid & 15;     // 16 col-groups of 8 -> 128 cols
#pragma unroll
    for (int k = 0; k < 16; ++k) {
        float4 a1 = *(const float4*)(As1 + k * 64 + (ty << 2));
        float4 a2 = *(const float4*)(As2 + k * 64 + (ty << 2));
        float4 b1l = *(const float4*)(Bs1 + k * 128 + (tx << 3));
        float4 b1h = *(const float4*)(Bs1 + k * 128 + (tx << 3) + 4);
        float4 b2l = *(const float4*)(Bs2 + k * 128 + (tx << 3));
        float4 b2h = *(const float4*)(Bs2 + k * 128 + (tx << 3) + 4);
        float av1[4] = {a1.x, a1.y, a1.z, a1.w};
        float av2[4] = {a2.x, a2.y, a2.z, a2.w};
        float bv1[8] = {b1l.x, b1l.y, b1l.z, b1l.w, b1h.x, b1h.y, b1h.z, b1h.w};
        float bv2[8] = {b2l.x, b2l.y, b2l.z, b2l.w, b2h.x, b2h.y, b2h.z, b2h.w};
#pragma unroll
        for (int u = 0; u < 4; ++u)
#pragma unroll
            for (int v = 0; v < 8; ++v)
                acc[u][v] += av1[u] * bv1[v] + av2[u] * bv2[v];
    }
    float bv[8];
#pragma unroll
    for (int v = 0; v < 8; ++v) bv[v] = bias[(tx << 3) + v];
#pragma unroll
    for (int u = 0; u < 4; ++u) {
        int m = m0 + (ty << 2) + u;
        ushort4 o0, o1;
        o0.x = f2bf(fmaxf(acc[u][0] + bv[0], 0.f));
        o0.y = f2bf(fmaxf(acc[u][1] + bv[1], 0.f));
        o0.z = f2bf(fmaxf(acc[u][2] + bv[2], 0.f));
        o0.w = f2bf(fmaxf(acc[u][3] + bv[3], 0.f));
        o1.x = f2bf(fmaxf(acc[u][4] + bv[4], 0.f));
        o1.y = f2bf(fmaxf(acc[u][5] + bv[5], 0.f));
        o1.z = f2bf(fmaxf(acc[u][6] + bv[6], 0.f));
        o1.w = f2bf(fmaxf(acc[u][7] + bv[7], 0.f));
        *(ushort4*)(Out + (size_t)m * 128 + (tx << 3)) = o0;
        *(ushort4*)(Out + (size_t)m * 128 + (tx << 3) + 4) = o1;
    }
}

// ---------------- aggregation bf16 (layers 1-2), 2-way edge split per node ----------
__global__ __launch_bounds__(256) void agg_bf16(const ushort_t* __restrict__ hin,
                                                ushort_t* __restrict__ agg,
                                                const int* __restrict__ rs,
                                                const int* __restrict__ esrc,
                                                int din, int sh) {
    int gid = blockIdx.x * 256 + threadIdx.x;
    int n = gid >> sh;
    int sub = gid & ((1 << sh) - 1);
    int half = 1 << (sh - 1);
    int c = (sub & (half - 1)) << 3;
    int par = sub >> (sh - 1);
    int e1 = uclamp(rs[n + 1], EDGES);
    int e0 = uclamp(rs[n], e1);
    float a[8] = {0.f,0.f,0.f,0.f,0.f,0.f,0.f,0.f};
    for (int e = e0 + par; e < e1; e += 2) {
        int s = uclamp(esrc[e], NODES - 1);
        u16x8 v = *(const u16x8*)(hin + (size_t)s * din + c);
#pragma unroll
        for (int k = 0; k < 8; ++k) a[k] += bf2f(v[k]);
    }
#pragma unroll
    for (int k = 0; k < 8; ++k) a[k] += __shfl_xor(a[k], half, 64);
    if (par == 0) {
        u16x8 o;
#pragma unroll
        for (int k = 0; k < 8; ++k) o[k] = f2bf(a[k]);
        *(u16x8*)(agg + (size_t)n * din + c) = o;
    }
}

// ---------------- MFMA dual-GEMM with LDS-staged weights (layers 1-2) ----------------
template<int KD>
__global__ __launch_bounds__(256) void gemm2(const ushort_t* __restrict__ A1,
                                             const ushort_t* __restrict__ A2,
                                             const ushort_t* __restrict__ W1,
                                             const ushort_t* __restrict__ W2,
                                             const float* __restrict__ bias,
                                             ushort_t* __restrict__ outp) {
    __shared__ ushort_t Ws1[64 * KD], Ws2[64 * KD];
    int tid = threadIdx.x;
    int m0 = blockIdx.y * 64;
    int n0 = blockIdx.x * 64;

    {   // stage weight tiles: coalesced global, swizzled LDS
        constexpr int VPM = 64 * KD / 8;
#pragma unroll
        for (int j = 0; j < VPM / 256; ++j) {
            int vi = j * 256 + tid;
            int row = vi / (KD / 8);
            int ch  = (vi % (KD / 8)) * 8;
            u16x8 w1 = *(const u16x8*)(W1 + (size_t)(n0 + row) * KD + ch);
            u16x8 w2 = *(const u16x8*)(W2 + (size_t)(n0 + row) * KD + ch);
            unsigned byte = ((unsigned)(row * KD + ch) * 2u)
                          ^ (((unsigned)(row & 7)) << 4);
            *(u16x8*)((char*)Ws1 + byte) = w1;
            *(u16x8*)((char*)Ws2 + byte) = w2;
        }
    }
    __syncthreads();

    int wave = tid >> 6, lane = tid & 63;
    int quad = lane >> 4, l16 = lane & 15;
    int ms = m0 + wave * 16;

    f32x4 acc[4] = {};
    const ushort_t* a1p = A1 + (size_t)(ms + l16) * KD + quad * 8;
    const ushort_t* a2p = A2 + (size_t)(ms + l16) * KD + quad * 8;

#pragma unroll
    for (int k0 = 0; k0 < KD; k0 += 32) {
        bf16x8 a1 = *(const bf16x8*)(a1p + k0);
        bf16x8 a2 = *(const bf16x8*)(a2p + k0);
#pragma unroll
        for (int nt = 0; nt < 4; ++nt) {
            int row = nt * 16 + l16;
            unsigned byte = ((unsigned)(row * KD + quad * 8 + k0) * 2u)
                          ^ (((unsigned)(row & 7)) << 4);
            bf16x8 u = *(const bf16x8*)((const char*)Ws1 + byte);
            bf16x8 v = *(const bf16x8*)((const char*)Ws2 + byte);
            acc[nt] = __builtin_amdgcn_mfma_f32_16x16x32_bf16(a1, u, acc[nt], 0, 0, 0);
            acc[nt] = __builtin_amdgcn_mfma_f32_16x16x32_bf16(a2, v, acc[nt], 0, 0, 0);
        }
    }
#pragma unroll
    for (int nt = 0; nt < 4; ++nt) {
        int n = n0 + nt * 16 + l16;
        float bb = bias[n];
#pragma unroll
        for (int r = 0; r < 4; ++r) {
            float v = fmaxf(acc[nt][r] + bb, 0.f);
            int m = ms + quad * 4 + r;
            outp[(size_t)m * 256 + n] = f2bf(v);
        }
    }
}

// ---------------- layer-3 GEMM: shared-A dual out, LDS-staged weights ----------------
__global__ __launch_bounds__(256) void gemm_l3(const ushort_t* __restrict__ A,
                                               const ushort_t* __restrict__ Wroot,
                                               const ushort_t* __restrict__ Wrel,
                                               float* __restrict__ Q3,
                                               float* __restrict__ P3) {
    constexpr int KD = 256;
    __shared__ ushort_t Ws1[64 * KD], Ws2[64 * KD];   // 64 KB
    int tid = threadIdx.x;
    int ms = blockIdx.y * 64 + (tid >> 6) * 16;

    {
        constexpr int VPM = 64 * KD / 8;
#pragma unroll
        for (int j = 0; j < VPM / 256; ++j) {
            int vi = j * 256 + tid;
            int row = vi / (KD / 8);
            int ch  = (vi % (KD / 8)) * 8;
            u16x8 w1 = *(const u16x8*)(Wroot + (size_t)row * KD + ch);
            u16x8 w2 = *(const u16x8*)(Wrel + (size_t)row * KD + ch);
            unsigned byte = ((unsigned)(row * KD + ch) * 2u)
                          ^ (((unsigned)(row & 7)) << 4);
            *(u16x8*)((char*)Ws1 + byte) = w1;
            *(u16x8*)((char*)Ws2 + byte) = w2;
        }
    }
    __syncthreads();

    int lane = tid & 63;
    int quad = lane >> 4, l16 = lane & 15;

    f32x4 accQ[4] = {};
    f32x4 accP[4] = {};
    const ushort_t* ap = A + (size_t)(ms + l16) * KD + quad * 8;

#pragma unroll
    for (int k0 = 0; k0 < KD; k0 += 32) {
        bf16x8 a = *(const bf16x8*)(ap + k0);
#pragma unroll
        for (int nt = 0; nt < 4; ++nt) {
            int row = nt * 16 + l16;
            unsigned byte = ((unsigned)(row * KD + quad * 8 + k0) * 2u)
                          ^ (((unsigned)(row & 7)) << 4);
            bf16x8 u = *(const bf16x8*)((const char*)Ws1 + byte);
            bf16x8 v = *(const bf16x8*)((const char*)Ws2 + byte);
            accQ[nt] = __builtin_amdgcn_mfma_f32_16x16x32_bf16(a, u, accQ[nt], 0, 0, 0);
            accP[nt] = __builtin_amdgcn_mfma_f32_16x16x32_bf16(a, v, accP[nt], 0, 0, 0);
        }
    }
#pragma unroll
    for (int nt = 0; nt < 4; ++nt) {
        int n = nt * 16 + l16;
#pragma unroll
        for (int r = 0; r < 4; ++r) {
            int m = ms + quad * 4 + r;
            Q3[(size_t)m * 64 + n] = accQ[nt][r];
            P3[(size_t)m * 64 + n] = accP[nt][r];
        }
    }
}

// ---------------- layer-3 aggregate + bias + hi/lo split (2-way edge split) ---------
__global__ __launch_bounds__(256) void agg_final(const float* __restrict__ P3,
                                                 const float* __restrict__ Q3,
                                                 const float* __restrict__ bias,
                                                 const int* __restrict__ rs,
                                                 const int* __restrict__ esrc,
                                                 ushort_t* __restrict__ h4hi,
                                                 ushort_t* __restrict__ h4lo) {
    int gid = blockIdx.x * 256 + threadIdx.x;     // 0..524287
    int n = gid >> 5;
    int sub = gid & 31;
    int c = (sub & 15) << 2;
    int par = sub >> 4;
    int e1 = uclamp(rs[n + 1], EDGES);
    int e0 = uclamp(rs[n], e1);
    float4 acc = {0.f, 0.f, 0.f, 0.f};
    for (int e = e0 + par; e < e1; e += 2) {
        int s = uclamp(esrc[e], NODES - 1);
        float4 v = *(const float4*)(P3 + (size_t)s * 64 + c);
        acc.x += v.x; acc.y += v.y; acc.z += v.z; acc.w += v.w;
    }
    acc.x += __shfl_xor(acc.x, 16, 64);
    acc.y += __shfl_xor(acc.y, 16, 64);
    acc.z += __shfl_xor(acc.z, 16, 64);
    acc.w += __shfl_xor(acc.w, 16, 64);
    if (par == 0) {
        float4 q = *(const float4*)(Q3 + (size_t)n * 64 + c);
        float4 bb = *(const float4*)(bias + c);
        float v0 = acc.x + q.x + bb.x;
        float v1 = acc.y + q.y + bb.y;
        float v2 = acc.z + q.z + bb.z;
        float v3 = acc.w + q.w + bb.w;
        ushort4 hi, lo;
        hi.x = f2bf(v0); lo.x = f2bf(v0 - bf2f(hi.x));
        hi.y = f2bf(v1); lo.y = f2bf(v1 - bf2f(hi.y));
        hi.z = f2bf(v2); lo.z = f2bf(v2 - bf2f(hi.z));
        hi.w = f2bf(v3); lo.w = f2bf(v3 - bf2f(hi.w));
        *(ushort4*)(h4hi + (size_t)n * 64 + c) = hi;
        *(ushort4*)(h4lo + (size_t)n * 64 + c) = lo;
    }
}

// ---------------- final Gram via split-bf16 MFMA: D = H·H^T, f32 out ----------------
__global__ __launch_bounds__(256) void final_mfma(const ushort_t* __restrict__ Hhi,
                                                  const ushort_t* __restrict__ Hlo,
                                                  float* __restrict__ out) {
    int tid = threadIdx.x;
    int wave = tid >> 6, lane = tid & 63;
    int quad = lane >> 4, l16 = lane & 15;
    int bz = blockIdx.z;
    int nbase = blockIdx.y * 64 + wave * 16;
    int m0 = blockIdx.x * 64;
    const ushort_t* Hbh = Hhi + (size_t)bz * NPTS * 64;
    const ushort_t* Hbl = Hlo + (size_t)bz * NPTS * 64;

    f32x4 acc[4] = {{0.f,0.f,0.f,0.f},{0.f,0.f,0.f,0.f},{0.f,0.f,0.f,0.f},{0.f,0.f,0.f,0.f}};
    const ushort_t* aph = Hbh + (size_t)(nbase + l16) * 64 + quad * 8;
    const ushort_t* apl = Hbl + (size_t)(nbase + l16) * 64 + quad * 8;
    const ushort_t* bph = Hbh + (size_t)(m0 + l16) * 64 + quad * 8;
    const ushort_t* bpl = Hbl + (size_t)(m0 + l16) * 64 + quad * 8;

#pragma unroll
    for (int k0 = 0; k0 < 64; k0 += 32) {
        bf16x8 ah = *(const bf16x8*)(aph + k0);
        bf16x8 al = *(const bf16x8*)(apl + k0);
#pragma unroll
        for (int nt = 0; nt < 4; ++nt) {
            bf16x8 bh = *(const bf16x8*)(bph + (size_t)nt * 16 * 64 + k0);
            bf16x8 bl = *(const bf16x8*)(bpl + (size_t)nt * 16 * 64 + k0);
            acc[nt] = __builtin_amdgcn_mfma_f32_16x16x32_bf16(ah, bh, acc[nt], 0, 0, 0);
            acc[nt] = __builtin_amdgcn_mfma_f32_16x16x32_bf16(ah, bl, acc[nt], 0, 0, 0);
            acc[nt] = __builtin_amdgcn_mfma_f32_16x16x32_bf16(al, bh, acc[nt], 0, 0, 0);
        }
    }
#pragma unroll
    for (int nt = 0; nt < 4; ++nt) {
#pragma unroll
        for (int r = 0; r < 4; ++r) {
            int n = nbase + quad * 4 + r;
            int m = m0 + nt * 16 + l16;
            out[((size_t)(bz * NPTS + n)) * NPTS + m] = acc[nt][r];
        }
    }
}

// ---------------- launch ----------------
extern "C" void kernel_launch(void* const* d_in, const int* in_sizes, int n_in,
                              void* d_out, int out_size, void* d_ws, size_t ws_size,
                              hipStream_t stream) {
    const float* x = (const float*)d_in[0];
    const float* W[12];
    for (int i = 0; i < 12; ++i) W[i] = (const float*)d_in[1 + i];
    float* out = (float*)d_out;

    // d_ws (~5.5 MB): h4 hi/lo + graph structs
    char* w = (char*)d_ws;
    ushort_t* h4hi = (ushort_t*)w; w += (size_t)NODES * 64 * 2;     // 2 MB
    ushort_t* h4lo = (ushort_t*)w; w += (size_t)NODES * 64 * 2;     // 2 MB
    int* nbors  = (int*)w;    w += (size_t)EDGES * 4;               // 640 KB
    int* cnt    = (int*)w;    w += (size_t)NODES * 4;               // 64 KB
    int* cur    = (int*)w;    w += (size_t)NODES * 4;               // 64 KB (contiguous after cnt)
    int* rs     = (int*)w;    w += (size_t)(NODES + 1) * 4 + 12;    // 64 KB
    int* esrc   = (int*)w;    w += (size_t)EDGES * 4;               // 640 KB

    // scratch inside d_out (64 MB, fully overwritten by final_mfma).
    // pd [1,11) + pi [12,17) MiB die after knn_merge; h1b ([1,5)) and h2b ([13,21))
    // are first written strictly after -> time-disjoint aliasing is safe.
    char* ob = (char*)d_out;
    ushort_t* wb    = (ushort_t*)(ob + 0);                   // 448 KB bf16 weights
    float*    sqh   = (float*)   (ob + (size_t)512*1024);    // 64 KB (0.5*|x|^2)
    float*    pd    = (float*)   (ob + (size_t) 1u*1048576); // 10 MiB [node][jc(16)][10] f32
    ushort_t* pi_   = (ushort_t*)(ob + (size_t)12u*1048576); // 5 MiB
    ushort_t* h1b   = (ushort_t*)(ob + (size_t) 1u*1048576); // 4 MB  (aliases pd)
    ushort_t* h2b   = (ushort_t*)(ob + (size_t)13u*1048576); // 8 MB  (aliases pi)
    ushort_t* h3b   = (ushort_t*)(ob + (size_t)21u*1048576); // 8 MB
    float*    P3    = (float*)   (ob + (size_t)29u*1048576); // 4 MB f32 (h3.Wrel^T)
    float*    Q3    = (float*)   (ob + (size_t)33u*1048576); // 4 MB f32 (h3.Wroot^T)
    ushort_t* aggb  = (ushort_t*)(ob + (size_t)37u*1048576); // 8 MB bf16 agg

    cast_weights<<<896, 256, 0, stream>>>(W[3], W[4], W[6], W[7], W[9], W[10], wb, x, sqh, cnt);
    knn_partial<<<dim3(JCH, 8, BATCH), 128, 0, stream>>>(x, sqh, pd, pi_);
    knn_merge<<<1024, 256, 0, stream>>>(pd, pi_, nbors, cnt);   // fused in-degree count
    scan_kernel<<<1, 256, 0, stream>>>(cnt, rs);
    fill_kernel<<<EDGES / 256, 256, 0, stream>>>(nbors, rs, cur, esrc);

    // layer 0: K=16, N=128, f32 compute, fused neighbor-agg, bf16 out
    gemm_layer0<<<256, 256, 0, stream>>>(x, rs, esrc, W[0], W[1], W[2], h1b);
    // layer 1: K=128, N=256  (agg: 32 thr/node -> sh=5; gemm: LDS weights)
    agg_bf16<<<NODES * 32 / 256, 256, 0, stream>>>(h1b, aggb, rs, esrc, 128, 5);
    gemm2<128><<<dim3(4, 256), 256, 0, stream>>>(h1b, aggb, wb, wb + 32768, W[5], h2b);
    // layer 2: K=256, N=256  (agg: 64 thr/node -> sh=6)
    agg_bf16<<<NODES * 64 / 256, 256, 0, stream>>>(h2b, aggb, rs, esrc, 256, 6);
    gemm2<256><<<dim3(4, 256), 256, 0, stream>>>(h2b, aggb, wb + 65536, wb + 131072,
                                                 W[8], h3b);
    // layer 3: project first (LDS weights), then aggregate 64-dim rows
    gemm_l3<<<dim3(1, 256), 256, 0, stream>>>(h3b, wb + 196608, wb + 212992, Q3, P3);
    agg_final<<<NODES * 32 / 256, 256, 0, stream>>>(P3, Q3, W[11], rs, esrc, h4hi, h4lo);

    final_mfma<<<dim3(16, 16, 16), 256, 0, stream>>>(h4hi, h4lo, out);
}

// Round 10
// 309.535 us; speedup vs baseline: 1.0096x; 1.0096x over previous
//
#include <hip/hip_runtime.h>

#define BATCH 16
#define NPTS 1024
#define CIN 16
#define NODES (BATCH*NPTS)      // 16384
#define KNN 10
#define EDGES (NODES*KNN)       // 163840
#define JCH 8                   // j-chunks for KNN
#define JLEN (NPTS/JCH)         // 128

typedef unsigned short ushort_t;
typedef __attribute__((ext_vector_type(8))) short bf16x8;
typedef __attribute__((ext_vector_type(8))) unsigned short u16x8;
typedef __attribute__((ext_vector_type(4))) float f32x4;
typedef __attribute__((ext_vector_type(2))) float f32x2;

__device__ __forceinline__ int uclamp(int v, int hi) {
    return ((unsigned)v > (unsigned)hi) ? hi : v;
}
__device__ __forceinline__ float bf2f(ushort_t u) {
    union { unsigned int i; float f; } v; v.i = ((unsigned int)u) << 16; return v.f;
}
__device__ __forceinline__ ushort_t f2bf(float f) {
    union { float f; unsigned int i; } v; v.f = f;
    unsigned int r = (v.i + 0x7fffu + ((v.i >> 16) & 1u)) >> 16;
    return (ushort_t)r;
}

// ---------------- cast layer-1..3 weights f32 -> bf16 (229376 elems) ----------------
__global__ __launch_bounds__(256) void cast_weights(const float* __restrict__ s0,
                                                    const float* __restrict__ s1,
                                                    const float* __restrict__ s2,
                                                    const float* __restrict__ s3,
                                                    const float* __restrict__ s4,
                                                    const float* __restrict__ s5,
                                                    ushort_t* __restrict__ dst,
                                                    const float* __restrict__ xf,
                                                    float* __restrict__ sqh,
                                                    int* __restrict__ cntz) {
    int t = blockIdx.x * 256 + threadIdx.x;   // 896 blocks
    if (t < NODES) {
        const float4* xp = (const float4*)(xf + (size_t)t * 16);
        float4 a = xp[0], b = xp[1], c = xp[2], d = xp[3];
        float s = a.x*a.x + a.y*a.y + a.z*a.z + a.w*a.w
                + b.x*b.x + b.y*b.y + b.z*b.z + b.w*b.w
                + c.x*c.x + c.y*c.y + c.z*c.z + c.w*c.w
                + d.x*d.x + d.y*d.y + d.z*d.z + d.w*d.w;
        sqh[t] = 0.5f * s;
    }
    if (t < 2 * NODES) cntz[t] = 0;           // cnt (16384) + cur (16384), contiguous
    const float* s; int off;
    if      (t <  32768) { s = s0; off = 0; }
    else if (t <  65536) { s = s1; off = 32768; }
    else if (t < 131072) { s = s2; off = 65536; }
    else if (t < 196608) { s = s3; off = 131072; }
    else if (t < 212992) { s = s4; off = 196608; }
    else                 { s = s5; off = 212992; }
    dst[t] = f2bf(s[t - off]);
}

// ---------------- KNN phase A: per-(i, j-chunk) top-10 ----------------
// grid dim3(JCH=8, 8, BATCH) = 1024 blocks, 128 threads.
__global__ __launch_bounds__(128, 4) void knn_partial(const float* __restrict__ xf,
                                                      const float* __restrict__ sqh,
                                                      float* __restrict__ pd,
                                                      ushort_t* __restrict__ pi_) {
    int jc = blockIdx.x, ic = blockIdx.y, b = blockIdx.z;
    int tid = threadIdx.x;                    // 0..127
    int i_local = (ic << 7) | tid;
    const float* xbp = xf + (size_t)b * NPTS * CIN;
    const float* sqb = sqh + b * NPTS;

    f32x2 nxi[8];
    {
        const f32x2* xip = (const f32x2*)(xbp + (size_t)i_local * 16);
#pragma unroll
        for (int q = 0; q < 8; ++q) nxi[q] = -xip[q];
    }

    int jbase = jc * JLEN;
    const float* yb = xbp + (size_t)jbase * 16;   // wave-uniform base

    float bd[10]; int bi[10];
#pragma unroll
    for (int r = 0; r < 10; ++r) { bd[r] = 3.0e38f; bi[r] = 0; }

#pragma unroll 4
    for (int jl = 0; jl < JLEN; ++jl) {
        const f32x2* y2 = (const f32x2*)(yb + jl * 16);   // uniform -> s_load
        f32x2 acc2 = {sqb[jbase + jl], 0.0f};             // uniform scalar seed
#pragma unroll
        for (int d = 0; d < 8; ++d) acc2 = __builtin_elementwise_fma(nxi[d], y2[d], acc2);
        float dist = acc2.x + acc2.y;
        int j = jbase + jl;
        float c = (j != i_local) ? dist : 3.0e38f;
        bool m[10];
#pragma unroll
        for (int k = 0; k < 10; ++k) m[k] = c < bd[k];
#pragma unroll
        for (int k = 9; k >= 1; --k) {
            int t = m[k-1] ? bi[k-1] : j;
            bi[k] = m[k] ? t : bi[k];
            bd[k] = __builtin_amdgcn_fmed3f(c, bd[k-1], bd[k]);
        }
        bi[0] = m[0] ? j : bi[0];
        bd[0] = fminf(c, bd[0]);
    }
    size_t base = ((size_t)(b * NPTS + i_local) * JCH + jc) * 10;
#pragma unroll
    for (int r = 0; r < 10; ++r) { pd[base + r] = bd[r]; pi_[base + r] = (ushort_t)bi[r]; }
}

// ---------------- KNN phase B: lane-parallel merge, 8 lanes per node ----------------
__global__ __launch_bounds__(256) void knn_merge(const float* __restrict__ pd,
                                                 const ushort_t* __restrict__ pi_,
                                                 int* __restrict__ nbors,
                                                 int* __restrict__ cnt) {
    int tid = blockIdx.x * 256 + threadIdx.x;     // 0..131071
    int node = tid >> 3;                          // 0..16383
    int sub  = tid & 7;                           // list index (jc)
    int b = node >> 10, i = node & 1023;
    int lane = threadIdx.x & 63;

    size_t base = ((size_t)node * JCH + sub) * 10;
    float d[11]; int id[10];
    {
        const float2* dp = (const float2*)(pd + base);
        const unsigned int* ip = (const unsigned int*)(pi_ + base);
#pragma unroll
        for (int q = 0; q < 5; ++q) {
            float2 dv = dp[q];
            unsigned int iv = ip[q];
            d[2*q] = dv.x; d[2*q+1] = dv.y;
            id[2*q] = (int)(iv & 0xffffu); id[2*q+1] = (int)(iv >> 16);
        }
        d[10] = 3.0e38f;
    }

    int res[10];
#pragma unroll
    for (int r = 0; r < 10; ++r) {
        float hd = d[0]; int hl = sub;
#pragma unroll
        for (int mk = 1; mk <= 4; mk <<= 1) {
            float od = __shfl_xor(hd, mk, 64);
            int   ol = __shfl_xor(hl, mk, 64);
            bool take = (od < hd) || (od == hd && ol < hl);
            hd = take ? od : hd;
            hl = take ? ol : hl;
        }
        int src = (lane & 56) | hl;
        res[r] = __shfl(id[0], src, 64);
        bool win = (sub == hl);
#pragma unroll
        for (int k = 0; k < 9; ++k) {
            d[k]  = win ? d[k+1]  : d[k];
            id[k] = win ? id[k+1] : id[k];
        }
        d[9] = win ? d[10] : d[9];
    }

    if (sub == 0) {
        int gi = b * NPTS + i;
#pragma unroll
        for (int r = 0; r < 10; ++r) {
            int gdst = b * NPTS + uclamp(res[r], NPTS - 1);
            nbors[gi * KNN + r] = gdst;
            atomicAdd(&cnt[gdst], 1);
        }
    }
}

// ---------------- reverse-CSR build ----------------
__global__ __launch_bounds__(256) void scan_kernel(const int* __restrict__ cnt,
                                                   int* __restrict__ rs) {
    __shared__ int part[256];
    int t = threadIdx.x;
    int base = t << 6;
    int4 v[16];
    const int4* cp = (const int4*)(cnt + base);
#pragma unroll
    for (int q = 0; q < 16; ++q) v[q] = cp[q];
    int s = 0;
#pragma unroll
    for (int q = 0; q < 16; ++q) s += v[q].x + v[q].y + v[q].z + v[q].w;
    part[t] = s;
    __syncthreads();
    for (int off = 1; off < 256; off <<= 1) {
        int vv = (t >= off) ? part[t - off] : 0;
        __syncthreads();
        part[t] += vv;
        __syncthreads();
    }
    int run = part[t] - s;
    int4* rp = (int4*)(rs + base);
#pragma unroll
    for (int q = 0; q < 16; ++q) {
        int4 o;
        o.x = run; run += v[q].x;
        o.y = run; run += v[q].y;
        o.z = run; run += v[q].z;
        o.w = run; run += v[q].w;
        rp[q] = o;
    }
    if (t == 255) rs[NODES] = run;
}

__global__ __launch_bounds__(256) void fill_kernel(const int* __restrict__ nbors,
                                                   const int* __restrict__ rs,
                                                   int* __restrict__ cur,
                                                   int* __restrict__ esrc) {
    int e = blockIdx.x * 256 + threadIdx.x;
    if (e < EDGES) {
        int dst = uclamp(nbors[e], NODES - 1);
        int src = e / 10;
        int pos = atomicAdd(&cur[dst], 1);
        esrc[uclamp(rs[dst] + pos, EDGES - 1)] = src;
    }
}

// ---------------- layer-0 GEMM (f32 vector, K=16, N=128) + fused neighbor-agg -------
// grid 256 blocks x 256: block = 64 rows x all 128 cols. Gather uses index-preload:
// all esrc loads are address-independent -> issue together, then independent row loads.
__global__ __launch_bounds__(256) void gemm_layer0(const float* __restrict__ A1,
                                                   const int* __restrict__ rs,
                                                   const int* __restrict__ esrc,
                                                   const float* __restrict__ W1,
                                                   const float* __restrict__ W2,
                                                   const float* __restrict__ bias,
                                                   ushort_t* __restrict__ Out) {
    __shared__ float As1[16 * 64], As2[16 * 64], Bs1[16 * 128], Bs2[16 * 128];
    int tid = threadIdx.x;
    int m0 = blockIdx.x * 64;

    {   // stage x^T for this block's 64 rows
        int lr = tid >> 2, lc = (tid & 3) << 2;
        float4 a = *(const float4*)(A1 + (size_t)(m0 + lr) * 16 + lc);
        As1[(lc + 0) * 64 + lr] = a.x; As1[(lc + 1) * 64 + lr] = a.y;
        As1[(lc + 2) * 64 + lr] = a.z; As1[(lc + 3) * 64 + lr] = a.w;
    }
    {   // stage both weight matrices (128 x 16) transposed
        int wr = tid >> 1, wc = (tid & 1) << 3;
        float4 wa = *(const float4*)(W1 + (size_t)wr * 16 + wc);
        float4 wb = *(const float4*)(W1 + (size_t)wr * 16 + wc + 4);
        Bs1[(wc + 0) * 128 + wr] = wa.x; Bs1[(wc + 1) * 128 + wr] = wa.y;
        Bs1[(wc + 2) * 128 + wr] = wa.z; Bs1[(wc + 3) * 128 + wr] = wa.w;
        Bs1[(wc + 4) * 128 + wr] = wb.x; Bs1[(wc + 5) * 128 + wr] = wb.y;
        Bs1[(wc + 6) * 128 + wr] = wb.z; Bs1[(wc + 7) * 128 + wr] = wb.w;
        float4 va = *(const float4*)(W2 + (size_t)wr * 16 + wc);
        float4 vb = *(const float4*)(W2 + (size_t)wr * 16 + wc + 4);
        Bs2[(wc + 0) * 128 + wr] = va.x; Bs2[(wc + 1) * 128 + wr] = va.y;
        Bs2[(wc + 2) * 128 + wr] = va.z; Bs2[(wc + 3) * 128 + wr] = va.w;
        Bs2[(wc + 4) * 128 + wr] = vb.x; Bs2[(wc + 5) * 128 + wr] = vb.y;
        Bs2[(wc + 6) * 128 + wr] = vb.z; Bs2[(wc + 7) * 128 + wr] = vb.w;
    }
    {   // fused agg: 4 threads/row, 4 channels each; index-preload (cap 16)
        int r = tid >> 2;
        int c4 = (tid & 3) << 2;
        int n = m0 + r;
        int e1 = uclamp(rs[n + 1], EDGES);
        int e0 = uclamp(rs[n], e1);
        int m = e1 - e0;
        int mm = m < 16 ? m : 16;
        int idx[16];
#pragma unroll
        for (int t = 0; t < 16; ++t)
            idx[t] = (t < mm) ? uclamp(esrc[e0 + t], NODES - 1) : 0;
        float4 acc4 = {0.f, 0.f, 0.f, 0.f};
#pragma unroll
        for (int t = 0; t < 16; ++t) {
            if (t < mm) {
                float4 v = *(const float4*)(A1 + (size_t)idx[t] * 16 + c4);
                acc4.x += v.x; acc4.y += v.y; acc4.z += v.z; acc4.w += v.w;
            }
        }
        for (int e = e0 + 16; e < e1; ++e) {
            int s = uclamp(esrc[e], NODES - 1);
            float4 v = *(const float4*)(A1 + (size_t)s * 16 + c4);
            acc4.x += v.x; acc4.y += v.y; acc4.z += v.z; acc4.w += v.w;
        }
        As2[(c4 + 0) * 64 + r] = acc4.x; As2[(c4 + 1) * 64 + r] = acc4.y;
        As2[(c4 + 2) * 64 + r] = acc4.z; As2[(c4 + 3) * 64 + r] = acc4.w;
    }
    __syncthreads();

    float acc[4][8] = {};
    int ty = tid >> 4;     // 16 row-groups of 4 -> 64 rows
    int tx = tid & 15;     // 16 col-groups of 8 -> 128 cols
#pragma unroll
    for (int k = 0; k < 16; ++k) {
        float4 a1 = *(const float4*)(As1 + k * 64 + (ty << 2));
        float4 a2 = *(const float4*)(As2 + k * 64 + (ty << 2));
        float4 b1l = *(const float4*)(Bs1 + k * 128 + (tx << 3));
        float4 b1h = *(const float4*)(Bs1 + k * 128 + (tx << 3) + 4);
        float4 b2l = *(const float4*)(Bs2 + k * 128 + (tx << 3));
        float4 b2h = *(const float4*)(Bs2 + k * 128 + (tx << 3) + 4);
        float av1[4] = {a1.x, a1.y, a1.z, a1.w};
        float av2[4] = {a2.x, a2.y, a2.z, a2.w};
        float bv1[8] = {b1l.x, b1l.y, b1l.z, b1l.w, b1h.x, b1h.y, b1h.z, b1h.w};
        float bv2[8] = {b2l.x, b2l.y, b2l.z, b2l.w, b2h.x, b2h.y, b2h.z, b2h.w};
#pragma unroll
        for (int u = 0; u < 4; ++u)
#pragma unroll
            for (int v = 0; v < 8; ++v)
                acc[u][v] += av1[u] * bv1[v] + av2[u] * bv2[v];
    }
    float bv[8];
#pragma unroll
    for (int v = 0; v < 8; ++v) bv[v] = bias[(tx << 3) + v];
#pragma unroll
    for (int u = 0; u < 4; ++u) {
        int m = m0 + (ty << 2) + u;
        ushort4 o0, o1;
        o0.x = f2bf(fmaxf(acc[u][0] + bv[0], 0.f));
        o0.y = f2bf(fmaxf(acc[u][1] + bv[1], 0.f));
        o0.z = f2bf(fmaxf(acc[u][2] + bv[2], 0.f));
        o0.w = f2bf(fmaxf(acc[u][3] + bv[3], 0.f));
        o1.x = f2bf(fmaxf(acc[u][4] + bv[4], 0.f));
        o1.y = f2bf(fmaxf(acc[u][5] + bv[5], 0.f));
        o1.z = f2bf(fmaxf(acc[u][6] + bv[6], 0.f));
        o1.w = f2bf(fmaxf(acc[u][7] + bv[7], 0.f));
        *(ushort4*)(Out + (size_t)m * 128 + (tx << 3)) = o0;
        *(ushort4*)(Out + (size_t)m * 128 + (tx << 3) + 4) = o1;
    }
}

// ---------------- aggregation bf16 (layers 1-2), 2-way edge split + index preload ---
// sh = log2(threads/node). Thread: channel slice + edge parity; shfl_xor combine.
// esrc addresses are independent -> preload up to 12 indices, then 12 independent
// row gathers (breaks the serial latency chain that bounded r6 at ~490 GB/s).
__global__ __launch_bounds__(256) void agg_bf16(const ushort_t* __restrict__ hin,
                                                ushort_t* __restrict__ agg,
                                                const int* __restrict__ rs,
                                                const int* __restrict__ esrc,
                                                int din, int sh) {
    int gid = blockIdx.x * 256 + threadIdx.x;
    int n = gid >> sh;
    int sub = gid & ((1 << sh) - 1);
    int half = 1 << (sh - 1);
    int c = (sub & (half - 1)) << 3;
    int par = sub >> (sh - 1);
    int e1 = uclamp(rs[n + 1], EDGES);
    int e0 = uclamp(rs[n], e1);
    int ebase = e0 + par;
    int m = (e1 > ebase) ? ((e1 - ebase + 1) >> 1) : 0;
    int mm = m < 12 ? m : 12;
    int idx[12];
#pragma unroll
    for (int t = 0; t < 12; ++t)
        idx[t] = (t < mm) ? uclamp(esrc[ebase + 2 * t], NODES - 1) : 0;
    float a[8] = {0.f,0.f,0.f,0.f,0.f,0.f,0.f,0.f};
#pragma unroll
    for (int t = 0; t < 12; ++t) {
        if (t < mm) {
            u16x8 v = *(const u16x8*)(hin + (size_t)idx[t] * din + c);
#pragma unroll
            for (int k = 0; k < 8; ++k) a[k] += bf2f(v[k]);
        }
    }
    for (int e = ebase + 24; e < e1; e += 2) {
        int s = uclamp(esrc[e], NODES - 1);
        u16x8 v = *(const u16x8*)(hin + (size_t)s * din + c);
#pragma unroll
        for (int k = 0; k < 8; ++k) a[k] += bf2f(v[k]);
    }
#pragma unroll
    for (int k = 0; k < 8; ++k) a[k] += __shfl_xor(a[k], half, 64);
    if (par == 0) {
        u16x8 o;
#pragma unroll
        for (int k = 0; k < 8; ++k) o[k] = f2bf(a[k]);
        *(u16x8*)(agg + (size_t)n * din + c) = o;
    }
}

// ---------------- MFMA dual-GEMM with LDS-staged weights (layers 1-2) ----------------
template<int KD>
__global__ __launch_bounds__(256) void gemm2(const ushort_t* __restrict__ A1,
                                             const ushort_t* __restrict__ A2,
                                             const ushort_t* __restrict__ W1,
                                             const ushort_t* __restrict__ W2,
                                             const float* __restrict__ bias,
                                             ushort_t* __restrict__ outp) {
    __shared__ ushort_t Ws1[64 * KD], Ws2[64 * KD];
    int tid = threadIdx.x;
    int m0 = blockIdx.y * 64;
    int n0 = blockIdx.x * 64;

    {   // stage weight tiles: coalesced global, swizzled LDS
        constexpr int VPM = 64 * KD / 8;
#pragma unroll
        for (int j = 0; j < VPM / 256; ++j) {
            int vi = j * 256 + tid;
            int row = vi / (KD / 8);
            int ch  = (vi % (KD / 8)) * 8;
            u16x8 w1 = *(const u16x8*)(W1 + (size_t)(n0 + row) * KD + ch);
            u16x8 w2 = *(const u16x8*)(W2 + (size_t)(n0 + row) * KD + ch);
            unsigned byte = ((unsigned)(row * KD + ch) * 2u)
                          ^ (((unsigned)(row & 7)) << 4);
            *(u16x8*)((char*)Ws1 + byte) = w1;
            *(u16x8*)((char*)Ws2 + byte) = w2;
        }
    }
    __syncthreads();

    int wave = tid >> 6, lane = tid & 63;
    int quad = lane >> 4, l16 = lane & 15;
    int ms = m0 + wave * 16;

    f32x4 acc[4] = {};
    const ushort_t* a1p = A1 + (size_t)(ms + l16) * KD + quad * 8;
    const ushort_t* a2p = A2 + (size_t)(ms + l16) * KD + quad * 8;

#pragma unroll
    for (int k0 = 0; k0 < KD; k0 += 32) {
        bf16x8 a1 = *(const bf16x8*)(a1p + k0);
        bf16x8 a2 = *(const bf16x8*)(a2p + k0);
#pragma unroll
        for (int nt = 0; nt < 4; ++nt) {
            int row = nt * 16 + l16;
            unsigned byte = ((unsigned)(row * KD + quad * 8 + k0) * 2u)
                          ^ (((unsigned)(row & 7)) << 4);
            bf16x8 u = *(const bf16x8*)((const char*)Ws1 + byte);
            bf16x8 v = *(const bf16x8*)((const char*)Ws2 + byte);
            acc[nt] = __builtin_amdgcn_mfma_f32_16x16x32_bf16(a1, u, acc[nt], 0, 0, 0);
            acc[nt] = __builtin_amdgcn_mfma_f32_16x16x32_bf16(a2, v, acc[nt], 0, 0, 0);
        }
    }
#pragma unroll
    for (int nt = 0; nt < 4; ++nt) {
        int n = n0 + nt * 16 + l16;
        float bb = bias[n];
#pragma unroll
        for (int r = 0; r < 4; ++r) {
            float v = fmaxf(acc[nt][r] + bb, 0.f);
            int m = ms + quad * 4 + r;
            outp[(size_t)m * 256 + n] = f2bf(v);
        }
    }
}

// ---------------- layer-3 GEMM: shared-A dual out, LDS-staged weights ----------------
__global__ __launch_bounds__(256) void gemm_l3(const ushort_t* __restrict__ A,
                                               const ushort_t* __restrict__ Wroot,
                                               const ushort_t* __restrict__ Wrel,
                                               float* __restrict__ Q3,
                                               float* __restrict__ P3) {
    constexpr int KD = 256;
    __shared__ ushort_t Ws1[64 * KD], Ws2[64 * KD];   // 64 KB
    int tid = threadIdx.x;
    int ms = blockIdx.y * 64 + (tid >> 6) * 16;

    {
        constexpr int VPM = 64 * KD / 8;
#pragma unroll
        for (int j = 0; j < VPM / 256; ++j) {
            int vi = j * 256 + tid;
            int row = vi / (KD / 8);
            int ch  = (vi % (KD / 8)) * 8;
            u16x8 w1 = *(const u16x8*)(Wroot + (size_t)row * KD + ch);
            u16x8 w2 = *(const u16x8*)(Wrel + (size_t)row * KD + ch);
            unsigned byte = ((unsigned)(row * KD + ch) * 2u)
                          ^ (((unsigned)(row & 7)) << 4);
            *(u16x8*)((char*)Ws1 + byte) = w1;
            *(u16x8*)((char*)Ws2 + byte) = w2;
        }
    }
    __syncthreads();

    int lane = tid & 63;
    int quad = lane >> 4, l16 = lane & 15;

    f32x4 accQ[4] = {};
    f32x4 accP[4] = {};
    const ushort_t* ap = A + (size_t)(ms + l16) * KD + quad * 8;

#pragma unroll
    for (int k0 = 0; k0 < KD; k0 += 32) {
        bf16x8 a = *(const bf16x8*)(ap + k0);
#pragma unroll
        for (int nt = 0; nt < 4; ++nt) {
            int row = nt * 16 + l16;
            unsigned byte = ((unsigned)(row * KD + quad * 8 + k0) * 2u)
                          ^ (((unsigned)(row & 7)) << 4);
            bf16x8 u = *(const bf16x8*)((const char*)Ws1 + byte);
            bf16x8 v = *(const bf16x8*)((const char*)Ws2 + byte);
            accQ[nt] = __builtin_amdgcn_mfma_f32_16x16x32_bf16(a, u, accQ[nt], 0, 0, 0);
            accP[nt] = __builtin_amdgcn_mfma_f32_16x16x32_bf16(a, v, accP[nt], 0, 0, 0);
        }
    }
#pragma unroll
    for (int nt = 0; nt < 4; ++nt) {
        int n = nt * 16 + l16;
#pragma unroll
        for (int r = 0; r < 4; ++r) {
            int m = ms + quad * 4 + r;
            Q3[(size_t)m * 64 + n] = accQ[nt][r];
            P3[(size_t)m * 64 + n] = accP[nt][r];
        }
    }
}

// ---------------- layer-3 aggregate + bias + hi/lo split (2-way split + preload) ----
__global__ __launch_bounds__(256) void agg_final(const float* __restrict__ P3,
                                                 const float* __restrict__ Q3,
                                                 const float* __restrict__ bias,
                                                 const int* __restrict__ rs,
                                                 const int* __restrict__ esrc,
                                                 ushort_t* __restrict__ h4hi,
                                                 ushort_t* __restrict__ h4lo) {
    int gid = blockIdx.x * 256 + threadIdx.x;     // 0..524287
    int n = gid >> 5;
    int sub = gid & 31;
    int c = (sub & 15) << 2;
    int par = sub >> 4;
    int e1 = uclamp(rs[n + 1], EDGES);
    int e0 = uclamp(rs[n], e1);
    int ebase = e0 + par;
    int m = (e1 > ebase) ? ((e1 - ebase + 1) >> 1) : 0;
    int mm = m < 8 ? m : 8;
    int idx[8];
#pragma unroll
    for (int t = 0; t < 8; ++t)
        idx[t] = (t < mm) ? uclamp(esrc[ebase + 2 * t], NODES - 1) : 0;
    float4 acc = {0.f, 0.f, 0.f, 0.f};
#pragma unroll
    for (int t = 0; t < 8; ++t) {
        if (t < mm) {
            float4 v = *(const float4*)(P3 + (size_t)idx[t] * 64 + c);
            acc.x += v.x; acc.y += v.y; acc.z += v.z; acc.w += v.w;
        }
    }
    for (int e = ebase + 16; e < e1; e += 2) {
        int s = uclamp(esrc[e], NODES - 1);
        float4 v = *(const float4*)(P3 + (size_t)s * 64 + c);
        acc.x += v.x; acc.y += v.y; acc.z += v.z; acc.w += v.w;
    }
    acc.x += __shfl_xor(acc.x, 16, 64);
    acc.y += __shfl_xor(acc.y, 16, 64);
    acc.z += __shfl_xor(acc.z, 16, 64);
    acc.w += __shfl_xor(acc.w, 16, 64);
    if (par == 0) {
        float4 q = *(const float4*)(Q3 + (size_t)n * 64 + c);
        float4 bb = *(const float4*)(bias + c);
        float v0 = acc.x + q.x + bb.x;
        float v1 = acc.y + q.y + bb.y;
        float v2 = acc.z + q.z + bb.z;
        float v3 = acc.w + q.w + bb.w;
        ushort4 hi, lo;
        hi.x = f2bf(v0); lo.x = f2bf(v0 - bf2f(hi.x));
        hi.y = f2bf(v1); lo.y = f2bf(v1 - bf2f(hi.y));
        hi.z = f2bf(v2); lo.z = f2bf(v2 - bf2f(hi.z));
        hi.w = f2bf(v3); lo.w = f2bf(v3 - bf2f(hi.w));
        *(ushort4*)(h4hi + (size_t)n * 64 + c) = hi;
        *(ushort4*)(h4lo + (size_t)n * 64 + c) = lo;
    }
}

// ---------------- final Gram via split-bf16 MFMA: D = H·H^T, f32 out ----------------
__global__ __launch_bounds__(256) void final_mfma(const ushort_t* __restrict__ Hhi,
                                                  const ushort_t* __restrict__ Hlo,
                                                  float* __restrict__ out) {
    int tid = threadIdx.x;
    int wave = tid >> 6, lane = tid & 63;
    int quad = lane >> 4, l16 = lane & 15;
    int bz = blockIdx.z;
    int nbase = blockIdx.y * 64 + wave * 16;
    int m0 = blockIdx.x * 64;
    const ushort_t* Hbh = Hhi + (size_t)bz * NPTS * 64;
    const ushort_t* Hbl = Hlo + (size_t)bz * NPTS * 64;

    f32x4 acc[4] = {{0.f,0.f,0.f,0.f},{0.f,0.f,0.f,0.f},{0.f,0.f,0.f,0.f},{0.f,0.f,0.f,0.f}};
    const ushort_t* aph = Hbh + (size_t)(nbase + l16) * 64 + quad * 8;
    const ushort_t* apl = Hbl + (size_t)(nbase + l16) * 64 + quad * 8;
    const ushort_t* bph = Hbh + (size_t)(m0 + l16) * 64 + quad * 8;
    const ushort_t* bpl = Hbl + (size_t)(m0 + l16) * 64 + quad * 8;

#pragma unroll
    for (int k0 = 0; k0 < 64; k0 += 32) {
        bf16x8 ah = *(const bf16x8*)(aph + k0);
        bf16x8 al = *(const bf16x8*)(apl + k0);
#pragma unroll
        for (int nt = 0; nt < 4; ++nt) {
            bf16x8 bh = *(const bf16x8*)(bph + (size_t)nt * 16 * 64 + k0);
            bf16x8 bl = *(const bf16x8*)(bpl + (size_t)nt * 16 * 64 + k0);
            acc[nt] = __builtin_amdgcn_mfma_f32_16x16x32_bf16(ah, bh, acc[nt], 0, 0, 0);
            acc[nt] = __builtin_amdgcn_mfma_f32_16x16x32_bf16(ah, bl, acc[nt], 0, 0, 0);
            acc[nt] = __builtin_amdgcn_mfma_f32_16x16x32_bf16(al, bh, acc[nt], 0, 0, 0);
        }
    }
#pragma unroll
    for (int nt = 0; nt < 4; ++nt) {
#pragma unroll
        for (int r = 0; r < 4; ++r) {
            int n = nbase + quad * 4 + r;
            int m = m0 + nt * 16 + l16;
            out[((size_t)(bz * NPTS + n)) * NPTS + m] = acc[nt][r];
        }
    }
}

// ---------------- launch ----------------
extern "C" void kernel_launch(void* const* d_in, const int* in_sizes, int n_in,
                              void* d_out, int out_size, void* d_ws, size_t ws_size,
                              hipStream_t stream) {
    const float* x = (const float*)d_in[0];
    const float* W[12];
    for (int i = 0; i < 12; ++i) W[i] = (const float*)d_in[1 + i];
    float* out = (float*)d_out;

    // d_ws (~5.5 MB): h4 hi/lo + graph structs
    char* w = (char*)d_ws;
    ushort_t* h4hi = (ushort_t*)w; w += (size_t)NODES * 64 * 2;     // 2 MB
    ushort_t* h4lo = (ushort_t*)w; w += (size_t)NODES * 64 * 2;     // 2 MB
    int* nbors  = (int*)w;    w += (size_t)EDGES * 4;               // 640 KB
    int* cnt    = (int*)w;    w += (size_t)NODES * 4;               // 64 KB
    int* cur    = (int*)w;    w += (size_t)NODES * 4;               // 64 KB (contiguous after cnt)
    int* rs     = (int*)w;    w += (size_t)(NODES + 1) * 4 + 12;    // 64 KB
    int* esrc   = (int*)w;    w += (size_t)EDGES * 4;               // 640 KB

    // scratch inside d_out (64 MB, fully overwritten by final_mfma).
    // pd [1,6) + pi [6,8.5) MiB die after knn_merge; h1b ([1,5)) is first written
    // strictly after (stream-ordered) -> time-disjoint aliasing is safe.
    char* ob = (char*)d_out;
    ushort_t* wb    = (ushort_t*)(ob + 0);                   // 448 KB bf16 weights
    float*    sqh   = (float*)   (ob + (size_t)512*1024);    // 64 KB (0.5*|x|^2)
    float*    pd    = (float*)   (ob + (size_t) 1u*1048576); // 5 MiB [node][jc(8)][10] f32
    ushort_t* pi_   = (ushort_t*)(ob + (size_t) 6u*1048576); // 2.5 MiB
    ushort_t* h1b   = (ushort_t*)(ob + (size_t) 1u*1048576); // 4 MB  (aliases pd)
    ushort_t* h2b   = (ushort_t*)(ob + (size_t)13u*1048576); // 8 MB
    ushort_t* h3b   = (ushort_t*)(ob + (size_t)21u*1048576); // 8 MB
    float*    P3    = (float*)   (ob + (size_t)29u*1048576); // 4 MB f32 (h3.Wrel^T)
    float*    Q3    = (float*)   (ob + (size_t)33u*1048576); // 4 MB f32 (h3.Wroot^T)
    ushort_t* aggb  = (ushort_t*)(ob + (size_t)37u*1048576); // 8 MB bf16 agg

    cast_weights<<<896, 256, 0, stream>>>(W[3], W[4], W[6], W[7], W[9], W[10], wb, x, sqh, cnt);
    knn_partial<<<dim3(JCH, 8, BATCH), 128, 0, stream>>>(x, sqh, pd, pi_);
    knn_merge<<<512, 256, 0, stream>>>(pd, pi_, nbors, cnt);   // fused in-degree count
    scan_kernel<<<1, 256, 0, stream>>>(cnt, rs);
    fill_kernel<<<EDGES / 256, 256, 0, stream>>>(nbors, rs, cur, esrc);

    // layer 0: K=16, N=128, f32 compute, fused neighbor-agg, bf16 out
    gemm_layer0<<<256, 256, 0, stream>>>(x, rs, esrc, W[0], W[1], W[2], h1b);
    // layer 1: K=128, N=256  (agg: 32 thr/node -> sh=5; gemm: LDS weights)
    agg_bf16<<<NODES * 32 / 256, 256, 0, stream>>>(h1b, aggb, rs, esrc, 128, 5);
    gemm2<128><<<dim3(4, 256), 256, 0, stream>>>(h1b, aggb, wb, wb + 32768, W[5], h2b);
    // layer 2: K=256, N=256  (agg: 64 thr/node -> sh=6)
    agg_bf16<<<NODES * 64 / 256, 256, 0, stream>>>(h2b, aggb, rs, esrc, 256, 6);
    gemm2<256><<<dim3(4, 256), 256, 0, stream>>>(h2b, aggb, wb + 65536, wb + 131072,
                                                 W[8], h3b);
    // layer 3: project first (LDS weights), then aggregate 64-dim rows
    gemm_l3<<<dim3(1, 256), 256, 0, stream>>>(h3b, wb + 196608, wb + 212992, Q3, P3);
    agg_final<<<NODES * 32 / 256, 256, 0, stream>>>(P3, Q3, W[11], rs, esrc, h4hi, h4lo);

    final_mfma<<<dim3(16, 16, 16), 256, 0, stream>>>(h4hi, h4lo, out);
}

// Round 11
// 298.254 us; speedup vs baseline: 1.0478x; 1.0378x over previous
//
#include <hip/hip_runtime.h>

#define BATCH 16
#define NPTS 1024
#define CIN 16
#define NODES (BATCH*NPTS)      // 16384
#define KNN 10
#define EDGES (NODES*KNN)       // 163840
#define JCH 8                   // j-chunks for KNN
#define JLEN (NPTS/JCH)         // 128

typedef unsigned short ushort_t;
typedef __attribute__((ext_vector_type(8))) short bf16x8;
typedef __attribute__((ext_vector_type(8))) unsigned short u16x8;
typedef __attribute__((ext_vector_type(4))) float f32x4;
typedef __attribute__((ext_vector_type(2))) float f32x2;

__device__ __forceinline__ int uclamp(int v, int hi) {
    return ((unsigned)v > (unsigned)hi) ? hi : v;
}
__device__ __forceinline__ float bf2f(ushort_t u) {
    union { unsigned int i; float f; } v; v.i = ((unsigned int)u) << 16; return v.f;
}
__device__ __forceinline__ ushort_t f2bf(float f) {
    union { float f; unsigned int i; } v; v.f = f;
    unsigned int r = (v.i + 0x7fffu + ((v.i >> 16) & 1u)) >> 16;
    return (ushort_t)r;
}

// ---------------- cast layer-1..3 weights f32 -> bf16 (229376 elems) ----------------
__global__ __launch_bounds__(256) void cast_weights(const float* __restrict__ s0,
                                                    const float* __restrict__ s1,
                                                    const float* __restrict__ s2,
                                                    const float* __restrict__ s3,
                                                    const float* __restrict__ s4,
                                                    const float* __restrict__ s5,
                                                    ushort_t* __restrict__ dst,
                                                    const float* __restrict__ xf,
                                                    float* __restrict__ sqh,
                                                    int* __restrict__ cntz) {
    int t = blockIdx.x * 256 + threadIdx.x;   // 896 blocks
    if (t < NODES) {
        const float4* xp = (const float4*)(xf + (size_t)t * 16);
        float4 a = xp[0], b = xp[1], c = xp[2], d = xp[3];
        float s = a.x*a.x + a.y*a.y + a.z*a.z + a.w*a.w
                + b.x*b.x + b.y*b.y + b.z*b.z + b.w*b.w
                + c.x*c.x + c.y*c.y + c.z*c.z + c.w*c.w
                + d.x*d.x + d.y*d.y + d.z*d.z + d.w*d.w;
        sqh[t] = 0.5f * s;
    }
    if (t < 2 * NODES) cntz[t] = 0;           // cnt (16384) + cur (16384), contiguous
    const float* s; int off;
    if      (t <  32768) { s = s0; off = 0; }
    else if (t <  65536) { s = s1; off = 32768; }
    else if (t < 131072) { s = s2; off = 65536; }
    else if (t < 196608) { s = s3; off = 131072; }
    else if (t < 212992) { s = s4; off = 196608; }
    else                 { s = s5; off = 212992; }
    dst[t] = f2bf(s[t - off]);
}

// ---------------- KNN phase A: per-(i, j-chunk) top-10 ----------------
// grid dim3(JCH=8, 8, BATCH) = 1024 blocks, 128 threads.
__global__ __launch_bounds__(128, 4) void knn_partial(const float* __restrict__ xf,
                                                      const float* __restrict__ sqh,
                                                      float* __restrict__ pd,
                                                      ushort_t* __restrict__ pi_) {
    int jc = blockIdx.x, ic = blockIdx.y, b = blockIdx.z;
    int tid = threadIdx.x;                    // 0..127
    int i_local = (ic << 7) | tid;
    const float* xbp = xf + (size_t)b * NPTS * CIN;
    const float* sqb = sqh + b * NPTS;

    f32x2 nxi[8];
    {
        const f32x2* xip = (const f32x2*)(xbp + (size_t)i_local * 16);
#pragma unroll
        for (int q = 0; q < 8; ++q) nxi[q] = -xip[q];
    }

    int jbase = jc * JLEN;
    const float* yb = xbp + (size_t)jbase * 16;   // wave-uniform base

    float bd[10]; int bi[10];
#pragma unroll
    for (int r = 0; r < 10; ++r) { bd[r] = 3.0e38f; bi[r] = 0; }

#pragma unroll 4
    for (int jl = 0; jl < JLEN; ++jl) {
        const f32x2* y2 = (const f32x2*)(yb + jl * 16);   // uniform -> s_load
        f32x2 acc2 = {sqb[jbase + jl], 0.0f};             // uniform scalar seed
#pragma unroll
        for (int d = 0; d < 8; ++d) acc2 = __builtin_elementwise_fma(nxi[d], y2[d], acc2);
        float dist = acc2.x + acc2.y;
        int j = jbase + jl;
        float c = (j != i_local) ? dist : 3.0e38f;
        bool m[10];
#pragma unroll
        for (int k = 0; k < 10; ++k) m[k] = c < bd[k];
#pragma unroll
        for (int k = 9; k >= 1; --k) {
            int t = m[k-1] ? bi[k-1] : j;
            bi[k] = m[k] ? t : bi[k];
            bd[k] = __builtin_amdgcn_fmed3f(c, bd[k-1], bd[k]);
        }
        bi[0] = m[0] ? j : bi[0];
        bd[0] = fminf(c, bd[0]);
    }
    size_t base = ((size_t)(b * NPTS + i_local) * JCH + jc) * 10;
#pragma unroll
    for (int r = 0; r < 10; ++r) { pd[base + r] = bd[r]; pi_[base + r] = (ushort_t)bi[r]; }
}

// ---------------- KNN phase B: lane-parallel merge, 8 lanes per node ----------------
__global__ __launch_bounds__(256) void knn_merge(const float* __restrict__ pd,
                                                 const ushort_t* __restrict__ pi_,
                                                 int* __restrict__ nbors,
                                                 int* __restrict__ cnt) {
    int tid = blockIdx.x * 256 + threadIdx.x;     // 0..131071
    int node = tid >> 3;                          // 0..16383
    int sub  = tid & 7;                           // list index (jc)
    int b = node >> 10, i = node & 1023;
    int lane = threadIdx.x & 63;

    size_t base = ((size_t)node * JCH + sub) * 10;
    float d[11]; int id[10];
    {
        const float2* dp = (const float2*)(pd + base);
        const unsigned int* ip = (const unsigned int*)(pi_ + base);
#pragma unroll
        for (int q = 0; q < 5; ++q) {
            float2 dv = dp[q];
            unsigned int iv = ip[q];
            d[2*q] = dv.x; d[2*q+1] = dv.y;
            id[2*q] = (int)(iv & 0xffffu); id[2*q+1] = (int)(iv >> 16);
        }
        d[10] = 3.0e38f;
    }

    int res[10];
#pragma unroll
    for (int r = 0; r < 10; ++r) {
        float hd = d[0]; int hl = sub;
#pragma unroll
        for (int mk = 1; mk <= 4; mk <<= 1) {
            float od = __shfl_xor(hd, mk, 64);
            int   ol = __shfl_xor(hl, mk, 64);
            bool take = (od < hd) || (od == hd && ol < hl);
            hd = take ? od : hd;
            hl = take ? ol : hl;
        }
        int src = (lane & 56) | hl;
        res[r] = __shfl(id[0], src, 64);
        bool win = (sub == hl);
#pragma unroll
        for (int k = 0; k < 9; ++k) {
            d[k]  = win ? d[k+1]  : d[k];
            id[k] = win ? id[k+1] : id[k];
        }
        d[9] = win ? d[10] : d[9];
    }

    if (sub == 0) {
        int gi = b * NPTS + i;
#pragma unroll
        for (int r = 0; r < 10; ++r) {
            int gdst = b * NPTS + uclamp(res[r], NPTS - 1);
            nbors[gi * KNN + r] = gdst;
            atomicAdd(&cnt[gdst], 1);
        }
    }
}

// ---------------- reverse-CSR build ----------------
__global__ __launch_bounds__(256) void scan_kernel(const int* __restrict__ cnt,
                                                   int* __restrict__ rs) {
    __shared__ int part[256];
    int t = threadIdx.x;
    int base = t << 6;
    int4 v[16];
    const int4* cp = (const int4*)(cnt + base);
#pragma unroll
    for (int q = 0; q < 16; ++q) v[q] = cp[q];
    int s = 0;
#pragma unroll
    for (int q = 0; q < 16; ++q) s += v[q].x + v[q].y + v[q].z + v[q].w;
    part[t] = s;
    __syncthreads();
    for (int off = 1; off < 256; off <<= 1) {
        int vv = (t >= off) ? part[t - off] : 0;
        __syncthreads();
        part[t] += vv;
        __syncthreads();
    }
    int run = part[t] - s;
    int4* rp = (int4*)(rs + base);
#pragma unroll
    for (int q = 0; q < 16; ++q) {
        int4 o;
        o.x = run; run += v[q].x;
        o.y = run; run += v[q].y;
        o.z = run; run += v[q].z;
        o.w = run; run += v[q].w;
        rp[q] = o;
    }
    if (t == 255) rs[NODES] = run;
}

__global__ __launch_bounds__(256) void fill_kernel(const int* __restrict__ nbors,
                                                   const int* __restrict__ rs,
                                                   int* __restrict__ cur,
                                                   int* __restrict__ esrc) {
    int e = blockIdx.x * 256 + threadIdx.x;
    if (e < EDGES) {
        int dst = uclamp(nbors[e], NODES - 1);
        int src = e / 10;
        int pos = atomicAdd(&cur[dst], 1);
        esrc[uclamp(rs[dst] + pos, EDGES - 1)] = src;
    }
}

// ---------------- layer-0 GEMM (f32 vector, K=16, N=128) + fused neighbor-agg -------
__global__ __launch_bounds__(256) void gemm_layer0(const float* __restrict__ A1,
                                                   const int* __restrict__ rs,
                                                   const int* __restrict__ esrc,
                                                   const float* __restrict__ W1,
                                                   const float* __restrict__ W2,
                                                   const float* __restrict__ bias,
                                                   ushort_t* __restrict__ Out) {
    __shared__ float As1[16 * 64], As2[16 * 64], Bs1[16 * 128], Bs2[16 * 128];
    int tid = threadIdx.x;
    int m0 = blockIdx.x * 64;

    {   // stage x^T for this block's 64 rows
        int lr = tid >> 2, lc = (tid & 3) << 2;
        float4 a = *(const float4*)(A1 + (size_t)(m0 + lr) * 16 + lc);
        As1[(lc + 0) * 64 + lr] = a.x; As1[(lc + 1) * 64 + lr] = a.y;
        As1[(lc + 2) * 64 + lr] = a.z; As1[(lc + 3) * 64 + lr] = a.w;
    }
    {   // stage both weight matrices (128 x 16) transposed
        int wr = tid >> 1, wc = (tid & 1) << 3;
        float4 wa = *(const float4*)(W1 + (size_t)wr * 16 + wc);
        float4 wb = *(const float4*)(W1 + (size_t)wr * 16 + wc + 4);
        Bs1[(wc + 0) * 128 + wr] = wa.x; Bs1[(wc + 1) * 128 + wr] = wa.y;
        Bs1[(wc + 2) * 128 + wr] = wa.z; Bs1[(wc + 3) * 128 + wr] = wa.w;
        Bs1[(wc + 4) * 128 + wr] = wb.x; Bs1[(wc + 5) * 128 + wr] = wb.y;
        Bs1[(wc + 6) * 128 + wr] = wb.z; Bs1[(wc + 7) * 128 + wr] = wb.w;
        float4 va = *(const float4*)(W2 + (size_t)wr * 16 + wc);
        float4 vb = *(const float4*)(W2 + (size_t)wr * 16 + wc + 4);
        Bs2[(wc + 0) * 128 + wr] = va.x; Bs2[(wc + 1) * 128 + wr] = va.y;
        Bs2[(wc + 2) * 128 + wr] = va.z; Bs2[(wc + 3) * 128 + wr] = va.w;
        Bs2[(wc + 4) * 128 + wr] = vb.x; Bs2[(wc + 5) * 128 + wr] = vb.y;
        Bs2[(wc + 6) * 128 + wr] = vb.z; Bs2[(wc + 7) * 128 + wr] = vb.w;
    }
    {   // fused agg: 4 threads/row, 4 channels each; index-preload (cap 16)
        int r = tid >> 2;
        int c4 = (tid & 3) << 2;
        int n = m0 + r;
        int e1 = uclamp(rs[n + 1], EDGES);
        int e0 = uclamp(rs[n], e1);
        int m = e1 - e0;
        int mm = m < 16 ? m : 16;
        int idx[16];
#pragma unroll
        for (int t = 0; t < 16; ++t)
            idx[t] = (t < mm) ? uclamp(esrc[e0 + t], NODES - 1) : 0;
        float4 acc4 = {0.f, 0.f, 0.f, 0.f};
#pragma unroll
        for (int t = 0; t < 16; ++t) {
            if (t < mm) {
                float4 v = *(const float4*)(A1 + (size_t)idx[t] * 16 + c4);
                acc4.x += v.x; acc4.y += v.y; acc4.z += v.z; acc4.w += v.w;
            }
        }
        for (int e = e0 + 16; e < e1; ++e) {
            int s = uclamp(esrc[e], NODES - 1);
            float4 v = *(const float4*)(A1 + (size_t)s * 16 + c4);
            acc4.x += v.x; acc4.y += v.y; acc4.z += v.z; acc4.w += v.w;
        }
        As2[(c4 + 0) * 64 + r] = acc4.x; As2[(c4 + 1) * 64 + r] = acc4.y;
        As2[(c4 + 2) * 64 + r] = acc4.z; As2[(c4 + 3) * 64 + r] = acc4.w;
    }
    __syncthreads();

    float acc[4][8] = {};
    int ty = tid >> 4;     // 16 row-groups of 4 -> 64 rows
    int tx = tid & 15;     // 16 col-groups of 8 -> 128 cols
#pragma unroll
    for (int k = 0; k < 16; ++k) {
        float4 a1 = *(const float4*)(As1 + k * 64 + (ty << 2));
        float4 a2 = *(const float4*)(As2 + k * 64 + (ty << 2));
        float4 b1l = *(const float4*)(Bs1 + k * 128 + (tx << 3));
        float4 b1h = *(const float4*)(Bs1 + k * 128 + (tx << 3) + 4);
        float4 b2l = *(const float4*)(Bs2 + k * 128 + (tx << 3));
        float4 b2h = *(const float4*)(Bs2 + k * 128 + (tx << 3) + 4);
        float av1[4] = {a1.x, a1.y, a1.z, a1.w};
        float av2[4] = {a2.x, a2.y, a2.z, a2.w};
        float bv1[8] = {b1l.x, b1l.y, b1l.z, b1l.w, b1h.x, b1h.y, b1h.z, b1h.w};
        float bv2[8] = {b2l.x, b2l.y, b2l.z, b2l.w, b2h.x, b2h.y, b2h.z, b2h.w};
#pragma unroll
        for (int u = 0; u < 4; ++u)
#pragma unroll
            for (int v = 0; v < 8; ++v)
                acc[u][v] += av1[u] * bv1[v] + av2[u] * bv2[v];
    }
    float bv[8];
#pragma unroll
    for (int v = 0; v < 8; ++v) bv[v] = bias[(tx << 3) + v];
#pragma unroll
    for (int u = 0; u < 4; ++u) {
        int m = m0 + (ty << 2) + u;
        ushort4 o0, o1;
        o0.x = f2bf(fmaxf(acc[u][0] + bv[0], 0.f));
        o0.y = f2bf(fmaxf(acc[u][1] + bv[1], 0.f));
        o0.z = f2bf(fmaxf(acc[u][2] + bv[2], 0.f));
        o0.w = f2bf(fmaxf(acc[u][3] + bv[3], 0.f));
        o1.x = f2bf(fmaxf(acc[u][4] + bv[4], 0.f));
        o1.y = f2bf(fmaxf(acc[u][5] + bv[5], 0.f));
        o1.z = f2bf(fmaxf(acc[u][6] + bv[6], 0.f));
        o1.w = f2bf(fmaxf(acc[u][7] + bv[7], 0.f));
        *(ushort4*)(Out + (size_t)m * 128 + (tx << 3)) = o0;
        *(ushort4*)(Out + (size_t)m * 128 + (tx << 3) + 4) = o1;
    }
}

// ---------------- aggregation bf16 (layers 1-2), 2-way edge split + index preload ---
__global__ __launch_bounds__(256) void agg_bf16(const ushort_t* __restrict__ hin,
                                                ushort_t* __restrict__ agg,
                                                const int* __restrict__ rs,
                                                const int* __restrict__ esrc,
                                                int din, int sh) {
    int gid = blockIdx.x * 256 + threadIdx.x;
    int n = gid >> sh;
    int sub = gid & ((1 << sh) - 1);
    int half = 1 << (sh - 1);
    int c = (sub & (half - 1)) << 3;
    int par = sub >> (sh - 1);
    int e1 = uclamp(rs[n + 1], EDGES);
    int e0 = uclamp(rs[n], e1);
    int ebase = e0 + par;
    int m = (e1 > ebase) ? ((e1 - ebase + 1) >> 1) : 0;
    int mm = m < 12 ? m : 12;
    int idx[12];
#pragma unroll
    for (int t = 0; t < 12; ++t)
        idx[t] = (t < mm) ? uclamp(esrc[ebase + 2 * t], NODES - 1) : 0;
    float a[8] = {0.f,0.f,0.f,0.f,0.f,0.f,0.f,0.f};
#pragma unroll
    for (int t = 0; t < 12; ++t) {
        if (t < mm) {
            u16x8 v = *(const u16x8*)(hin + (size_t)idx[t] * din + c);
#pragma unroll
            for (int k = 0; k < 8; ++k) a[k] += bf2f(v[k]);
        }
    }
    for (int e = ebase + 24; e < e1; e += 2) {
        int s = uclamp(esrc[e], NODES - 1);
        u16x8 v = *(const u16x8*)(hin + (size_t)s * din + c);
#pragma unroll
        for (int k = 0; k < 8; ++k) a[k] += bf2f(v[k]);
    }
#pragma unroll
    for (int k = 0; k < 8; ++k) a[k] += __shfl_xor(a[k], half, 64);
    if (par == 0) {
        u16x8 o;
#pragma unroll
        for (int k = 0; k < 8; ++k) o[k] = f2bf(a[k]);
        *(u16x8*)(agg + (size_t)n * din + c) = o;
    }
}

// ---------------- MFMA dual-GEMM with LDS-staged weights (layers 1-2) ----------------
template<int KD>
__global__ __launch_bounds__(256) void gemm2(const ushort_t* __restrict__ A1,
                                             const ushort_t* __restrict__ A2,
                                             const ushort_t* __restrict__ W1,
                                             const ushort_t* __restrict__ W2,
                                             const float* __restrict__ bias,
                                             ushort_t* __restrict__ outp) {
    __shared__ ushort_t Ws1[64 * KD], Ws2[64 * KD];
    int tid = threadIdx.x;
    int m0 = blockIdx.y * 64;
    int n0 = blockIdx.x * 64;

    {   // stage weight tiles: coalesced global, swizzled LDS
        constexpr int VPM = 64 * KD / 8;
#pragma unroll
        for (int j = 0; j < VPM / 256; ++j) {
            int vi = j * 256 + tid;
            int row = vi / (KD / 8);
            int ch  = (vi % (KD / 8)) * 8;
            u16x8 w1 = *(const u16x8*)(W1 + (size_t)(n0 + row) * KD + ch);
            u16x8 w2 = *(const u16x8*)(W2 + (size_t)(n0 + row) * KD + ch);
            unsigned byte = ((unsigned)(row * KD + ch) * 2u)
                          ^ (((unsigned)(row & 7)) << 4);
            *(u16x8*)((char*)Ws1 + byte) = w1;
            *(u16x8*)((char*)Ws2 + byte) = w2;
        }
    }
    __syncthreads();

    int wave = tid >> 6, lane = tid & 63;
    int quad = lane >> 4, l16 = lane & 15;
    int ms = m0 + wave * 16;

    f32x4 acc[4] = {};
    const ushort_t* a1p = A1 + (size_t)(ms + l16) * KD + quad * 8;
    const ushort_t* a2p = A2 + (size_t)(ms + l16) * KD + quad * 8;

#pragma unroll
    for (int k0 = 0; k0 < KD; k0 += 32) {
        bf16x8 a1 = *(const bf16x8*)(a1p + k0);
        bf16x8 a2 = *(const bf16x8*)(a2p + k0);
#pragma unroll
        for (int nt = 0; nt < 4; ++nt) {
            int row = nt * 16 + l16;
            unsigned byte = ((unsigned)(row * KD + quad * 8 + k0) * 2u)
                          ^ (((unsigned)(row & 7)) << 4);
            bf16x8 u = *(const bf16x8*)((const char*)Ws1 + byte);
            bf16x8 v = *(const bf16x8*)((const char*)Ws2 + byte);
            acc[nt] = __builtin_amdgcn_mfma_f32_16x16x32_bf16(a1, u, acc[nt], 0, 0, 0);
            acc[nt] = __builtin_amdgcn_mfma_f32_16x16x32_bf16(a2, v, acc[nt], 0, 0, 0);
        }
    }
#pragma unroll
    for (int nt = 0; nt < 4; ++nt) {
        int n = n0 + nt * 16 + l16;
        float bb = bias[n];
#pragma unroll
        for (int r = 0; r < 4; ++r) {
            float v = fmaxf(acc[nt][r] + bb, 0.f);
            int m = ms + quad * 4 + r;
            outp[(size_t)m * 256 + n] = f2bf(v);
        }
    }
}

// ---------------- layer-3 GEMM: shared-A dual out, LDS-staged weights ----------------
__global__ __launch_bounds__(256) void gemm_l3(const ushort_t* __restrict__ A,
                                               const ushort_t* __restrict__ Wroot,
                                               const ushort_t* __restrict__ Wrel,
                                               float* __restrict__ Q3,
                                               float* __restrict__ P3) {
    constexpr int KD = 256;
    __shared__ ushort_t Ws1[64 * KD], Ws2[64 * KD];   // 64 KB
    int tid = threadIdx.x;
    int ms = blockIdx.y * 64 + (tid >> 6) * 16;

    {
        constexpr int VPM = 64 * KD / 8;
#pragma unroll
        for (int j = 0; j < VPM / 256; ++j) {
            int vi = j * 256 + tid;
            int row = vi / (KD / 8);
            int ch  = (vi % (KD / 8)) * 8;
            u16x8 w1 = *(const u16x8*)(Wroot + (size_t)row * KD + ch);
            u16x8 w2 = *(const u16x8*)(Wrel + (size_t)row * KD + ch);
            unsigned byte = ((unsigned)(row * KD + ch) * 2u)
                          ^ (((unsigned)(row & 7)) << 4);
            *(u16x8*)((char*)Ws1 + byte) = w1;
            *(u16x8*)((char*)Ws2 + byte) = w2;
        }
    }
    __syncthreads();

    int lane = tid & 63;
    int quad = lane >> 4, l16 = lane & 15;

    f32x4 accQ[4] = {};
    f32x4 accP[4] = {};
    const ushort_t* ap = A + (size_t)(ms + l16) * KD + quad * 8;

#pragma unroll
    for (int k0 = 0; k0 < KD; k0 += 32) {
        bf16x8 a = *(const bf16x8*)(ap + k0);
#pragma unroll
        for (int nt = 0; nt < 4; ++nt) {
            int row = nt * 16 + l16;
            unsigned byte = ((unsigned)(row * KD + quad * 8 + k0) * 2u)
                          ^ (((unsigned)(row & 7)) << 4);
            bf16x8 u = *(const bf16x8*)((const char*)Ws1 + byte);
            bf16x8 v = *(const bf16x8*)((const char*)Ws2 + byte);
            accQ[nt] = __builtin_amdgcn_mfma_f32_16x16x32_bf16(a, u, accQ[nt], 0, 0, 0);
            accP[nt] = __builtin_amdgcn_mfma_f32_16x16x32_bf16(a, v, accP[nt], 0, 0, 0);
        }
    }
#pragma unroll
    for (int nt = 0; nt < 4; ++nt) {
        int n = nt * 16 + l16;
#pragma unroll
        for (int r = 0; r < 4; ++r) {
            int m = ms + quad * 4 + r;
            Q3[(size_t)m * 64 + n] = accQ[nt][r];
            P3[(size_t)m * 64 + n] = accP[nt][r];
        }
    }
}

// ---------------- layer-3 aggregate + bias + hi/lo split (2-way split + preload) ----
__global__ __launch_bounds__(256) void agg_final(const float* __restrict__ P3,
                                                 const float* __restrict__ Q3,
                                                 const float* __restrict__ bias,
                                                 const int* __restrict__ rs,
                                                 const int* __restrict__ esrc,
                                                 ushort_t* __restrict__ h4hi,
                                                 ushort_t* __restrict__ h4lo) {
    int gid = blockIdx.x * 256 + threadIdx.x;     // 0..524287
    int n = gid >> 5;
    int sub = gid & 31;
    int c = (sub & 15) << 2;
    int par = sub >> 4;
    int e1 = uclamp(rs[n + 1], EDGES);
    int e0 = uclamp(rs[n], e1);
    int ebase = e0 + par;
    int m = (e1 > ebase) ? ((e1 - ebase + 1) >> 1) : 0;
    int mm = m < 8 ? m : 8;
    int idx[8];
#pragma unroll
    for (int t = 0; t < 8; ++t)
        idx[t] = (t < mm) ? uclamp(esrc[ebase + 2 * t], NODES - 1) : 0;
    float4 acc = {0.f, 0.f, 0.f, 0.f};
#pragma unroll
    for (int t = 0; t < 8; ++t) {
        if (t < mm) {
            float4 v = *(const float4*)(P3 + (size_t)idx[t] * 64 + c);
            acc.x += v.x; acc.y += v.y; acc.z += v.z; acc.w += v.w;
        }
    }
    for (int e = ebase + 16; e < e1; e += 2) {
        int s = uclamp(esrc[e], NODES - 1);
        float4 v = *(const float4*)(P3 + (size_t)s * 64 + c);
        acc.x += v.x; acc.y += v.y; acc.z += v.z; acc.w += v.w;
    }
    acc.x += __shfl_xor(acc.x, 16, 64);
    acc.y += __shfl_xor(acc.y, 16, 64);
    acc.z += __shfl_xor(acc.z, 16, 64);
    acc.w += __shfl_xor(acc.w, 16, 64);
    if (par == 0) {
        float4 q = *(const float4*)(Q3 + (size_t)n * 64 + c);
        float4 bb = *(const float4*)(bias + c);
        float v0 = acc.x + q.x + bb.x;
        float v1 = acc.y + q.y + bb.y;
        float v2 = acc.z + q.z + bb.z;
        float v3 = acc.w + q.w + bb.w;
        ushort4 hi, lo;
        hi.x = f2bf(v0); lo.x = f2bf(v0 - bf2f(hi.x));
        hi.y = f2bf(v1); lo.y = f2bf(v1 - bf2f(hi.y));
        hi.z = f2bf(v2); lo.z = f2bf(v2 - bf2f(hi.z));
        hi.w = f2bf(v3); lo.w = f2bf(v3 - bf2f(hi.w));
        *(ushort4*)(h4hi + (size_t)n * 64 + c) = hi;
        *(ushort4*)(h4lo + (size_t)n * 64 + c) = lo;
    }
}

// ---------------- final Gram via split-bf16 MFMA: D = H·H^T, f32 out ----------------
// 128x128 output tile per block (grid 8x8x16 = 1024 blocks) -> H re-read traffic
// drops 268MB -> 67MB (each block reads 128 n-rows + 128 m-rows once).
// Wave covers 32 n-rows x 128 m-cols; B-fragments hoisted 8-wide per k-step.
__global__ __launch_bounds__(256) void final_mfma(const ushort_t* __restrict__ Hhi,
                                                  const ushort_t* __restrict__ Hlo,
                                                  float* __restrict__ out) {
    int tid = threadIdx.x;
    int wave = tid >> 6, lane = tid & 63;
    int quad = lane >> 4, l16 = lane & 15;
    int bz = blockIdx.z;
    int m0 = blockIdx.x * 128;
    int n0 = blockIdx.y * 128 + wave * 32;
    const ushort_t* Hbh = Hhi + (size_t)bz * NPTS * 64;
    const ushort_t* Hbl = Hlo + (size_t)bz * NPTS * 64;

    f32x4 acc[2][8] = {};
    const ushort_t* aph = Hbh + (size_t)(n0 + l16) * 64 + quad * 8;
    const ushort_t* apl = Hbl + (size_t)(n0 + l16) * 64 + quad * 8;
    const ushort_t* bph = Hbh + (size_t)(m0 + l16) * 64 + quad * 8;
    const ushort_t* bpl = Hbl + (size_t)(m0 + l16) * 64 + quad * 8;

#pragma unroll
    for (int k0 = 0; k0 < 64; k0 += 32) {
        bf16x8 bh[8], bl[8];
#pragma unroll
        for (int mt = 0; mt < 8; ++mt) {
            bh[mt] = *(const bf16x8*)(bph + (size_t)mt * 16 * 64 + k0);
            bl[mt] = *(const bf16x8*)(bpl + (size_t)mt * 16 * 64 + k0);
        }
#pragma unroll
        for (int nt = 0; nt < 2; ++nt) {
            bf16x8 ah = *(const bf16x8*)(aph + (size_t)nt * 16 * 64 + k0);
            bf16x8 al = *(const bf16x8*)(apl + (size_t)nt * 16 * 64 + k0);
#pragma unroll
            for (int mt = 0; mt < 8; ++mt) {
                acc[nt][mt] = __builtin_amdgcn_mfma_f32_16x16x32_bf16(ah, bh[mt], acc[nt][mt], 0, 0, 0);
                acc[nt][mt] = __builtin_amdgcn_mfma_f32_16x16x32_bf16(ah, bl[mt], acc[nt][mt], 0, 0, 0);
                acc[nt][mt] = __builtin_amdgcn_mfma_f32_16x16x32_bf16(al, bh[mt], acc[nt][mt], 0, 0, 0);
            }
        }
    }
#pragma unroll
    for (int nt = 0; nt < 2; ++nt)
#pragma unroll
        for (int mt = 0; mt < 8; ++mt)
#pragma unroll
            for (int r = 0; r < 4; ++r) {
                int n = n0 + nt * 16 + quad * 4 + r;
                int m = m0 + mt * 16 + l16;
                out[((size_t)(bz * NPTS + n)) * NPTS + m] = acc[nt][mt][r];
            }
}

// ---------------- launch ----------------
extern "C" void kernel_launch(void* const* d_in, const int* in_sizes, int n_in,
                              void* d_out, int out_size, void* d_ws, size_t ws_size,
                              hipStream_t stream) {
    const float* x = (const float*)d_in[0];
    const float* W[12];
    for (int i = 0; i < 12; ++i) W[i] = (const float*)d_in[1 + i];
    float* out = (float*)d_out;

    // d_ws (~5.5 MB): h4 hi/lo + graph structs
    char* w = (char*)d_ws;
    ushort_t* h4hi = (ushort_t*)w; w += (size_t)NODES * 64 * 2;     // 2 MB
    ushort_t* h4lo = (ushort_t*)w; w += (size_t)NODES * 64 * 2;     // 2 MB
    int* nbors  = (int*)w;    w += (size_t)EDGES * 4;               // 640 KB
    int* cnt    = (int*)w;    w += (size_t)NODES * 4;               // 64 KB
    int* cur    = (int*)w;    w += (size_t)NODES * 4;               // 64 KB (contiguous after cnt)
    int* rs     = (int*)w;    w += (size_t)(NODES + 1) * 4 + 12;    // 64 KB
    int* esrc   = (int*)w;    w += (size_t)EDGES * 4;               // 640 KB

    // scratch inside d_out (64 MB, fully overwritten by final_mfma).
    char* ob = (char*)d_out;
    ushort_t* wb    = (ushort_t*)(ob + 0);                   // 448 KB bf16 weights
    float*    sqh   = (float*)   (ob + (size_t)512*1024);    // 64 KB (0.5*|x|^2)
    float*    pd    = (float*)   (ob + (size_t) 1u*1048576); // 5 MiB [node][jc(8)][10] f32
    ushort_t* pi_   = (ushort_t*)(ob + (size_t) 6u*1048576); // 2.5 MiB
    ushort_t* h1b   = (ushort_t*)(ob + (size_t) 1u*1048576); // 4 MB  (aliases pd)
    ushort_t* h2b   = (ushort_t*)(ob + (size_t)13u*1048576); // 8 MB
    ushort_t* h3b   = (ushort_t*)(ob + (size_t)21u*1048576); // 8 MB
    float*    P3    = (float*)   (ob + (size_t)29u*1048576); // 4 MB f32 (h3.Wrel^T)
    float*    Q3    = (float*)   (ob + (size_t)33u*1048576); // 4 MB f32 (h3.Wroot^T)
    ushort_t* aggb  = (ushort_t*)(ob + (size_t)37u*1048576); // 8 MB bf16 agg

    cast_weights<<<896, 256, 0, stream>>>(W[3], W[4], W[6], W[7], W[9], W[10], wb, x, sqh, cnt);
    knn_partial<<<dim3(JCH, 8, BATCH), 128, 0, stream>>>(x, sqh, pd, pi_);
    knn_merge<<<512, 256, 0, stream>>>(pd, pi_, nbors, cnt);   // fused in-degree count
    scan_kernel<<<1, 256, 0, stream>>>(cnt, rs);
    fill_kernel<<<EDGES / 256, 256, 0, stream>>>(nbors, rs, cur, esrc);

    // layer 0: K=16, N=128, f32 compute, fused neighbor-agg, bf16 out
    gemm_layer0<<<256, 256, 0, stream>>>(x, rs, esrc, W[0], W[1], W[2], h1b);
    // layer 1: K=128, N=256  (agg: 32 thr/node -> sh=5; gemm: LDS weights)
    agg_bf16<<<NODES * 32 / 256, 256, 0, stream>>>(h1b, aggb, rs, esrc, 128, 5);
    gemm2<128><<<dim3(4, 256), 256, 0, stream>>>(h1b, aggb, wb, wb + 32768, W[5], h2b);
    // layer 2: K=256, N=256  (agg: 64 thr/node -> sh=6)
    agg_bf16<<<NODES * 64 / 256, 256, 0, stream>>>(h2b, aggb, rs, esrc, 256, 6);
    gemm2<256><<<dim3(4, 256), 256, 0, stream>>>(h2b, aggb, wb + 65536, wb + 131072,
                                                 W[8], h3b);
    // layer 3: project first (LDS weights), then aggregate 64-dim rows
    gemm_l3<<<dim3(1, 256), 256, 0, stream>>>(h3b, wb + 196608, wb + 212992, Q3, P3);
    agg_final<<<NODES * 32 / 256, 256, 0, stream>>>(P3, Q3, W[11], rs, esrc, h4hi, h4lo);

    final_mfma<<<dim3(8, 8, 16), 256, 0, stream>>>(h4hi, h4lo, out);
}

// Round 13
// 295.158 us; speedup vs baseline: 1.0588x; 1.0105x over previous
//
#include <hip/hip_runtime.h>

#define BATCH 16
#define NPTS 1024
#define CIN 16
#define NODES (BATCH*NPTS)      // 16384
#define KNN 10
#define EDGES (NODES*KNN)       // 163840
#define JCH 8                   // j-chunks for KNN
#define JLEN (NPTS/JCH)         // 128

typedef unsigned short ushort_t;
typedef __attribute__((ext_vector_type(8))) short bf16x8;
typedef __attribute__((ext_vector_type(8))) unsigned short u16x8;
typedef __attribute__((ext_vector_type(4))) float f32x4;
typedef __attribute__((ext_vector_type(2))) float f32x2;

__device__ __forceinline__ int uclamp(int v, int hi) {
    return ((unsigned)v > (unsigned)hi) ? hi : v;
}
__device__ __forceinline__ float bf2f(ushort_t u) {
    union { unsigned int i; float f; } v; v.i = ((unsigned int)u) << 16; return v.f;
}
__device__ __forceinline__ ushort_t f2bf(float f) {
    union { float f; unsigned int i; } v; v.f = f;
    unsigned int r = (v.i + 0x7fffu + ((v.i >> 16) & 1u)) >> 16;
    return (ushort_t)r;
}

// ---------------- KNN phase A: per-(i, j-chunk) top-10 ----------------
// grid dim3(JCH=8, 8, BATCH) = 1024 blocks, 128 threads.
// Fold-ins: zero cnt/cur (completes before knn_merge starts, stream-ordered);
// per-block 0.5*|x_j|^2 computed in LDS (sqh buffer removed).
__global__ __launch_bounds__(128, 4) void knn_partial(const float* __restrict__ xf,
                                                      float* __restrict__ pd,
                                                      ushort_t* __restrict__ pi_,
                                                      int* __restrict__ cntz) {
    __shared__ float sqs[JLEN];
    int jc = blockIdx.x, ic = blockIdx.y, b = blockIdx.z;
    int tid = threadIdx.x;                    // 0..127
    {   // fold-in: zero cnt (16384) + cur (16384), contiguous
        int gtid = (((b << 3) | ic) * JCH + jc) * 128 + tid;   // 0..131071
        if (gtid < 2 * NODES) cntz[gtid] = 0;
    }
    int i_local = (ic << 7) | tid;
    const float* xbp = xf + (size_t)b * NPTS * CIN;

    int jbase = jc * JLEN;
    const float* yb = xbp + (size_t)jbase * 16;   // wave-uniform base

    {   // per-block sq of the 128 j-rows (thread t -> row t)
        const float4* rp = (const float4*)(yb + (size_t)tid * 16);
        float4 a = rp[0], b4 = rp[1], c4 = rp[2], d4 = rp[3];
        float s = a.x*a.x + a.y*a.y + a.z*a.z + a.w*a.w
                + b4.x*b4.x + b4.y*b4.y + b4.z*b4.z + b4.w*b4.w
                + c4.x*c4.x + c4.y*c4.y + c4.z*c4.z + c4.w*c4.w
                + d4.x*d4.x + d4.y*d4.y + d4.z*d4.z + d4.w*d4.w;
        sqs[tid] = 0.5f * s;
    }

    f32x2 nxi[8];
    {
        const f32x2* xip = (const f32x2*)(xbp + (size_t)i_local * 16);
#pragma unroll
        for (int q = 0; q < 8; ++q) nxi[q] = -xip[q];
    }
    __syncthreads();

    float bd[10]; int bi[10];
#pragma unroll
    for (int r = 0; r < 10; ++r) { bd[r] = 3.0e38f; bi[r] = 0; }

#pragma unroll 4
    for (int jl = 0; jl < JLEN; ++jl) {
        const f32x2* y2 = (const f32x2*)(yb + jl * 16);   // uniform -> s_load
        f32x2 acc2 = {sqs[jl], 0.0f};                     // uniform LDS broadcast seed
#pragma unroll
        for (int d = 0; d < 8; ++d) acc2 = __builtin_elementwise_fma(nxi[d], y2[d], acc2);
        float dist = acc2.x + acc2.y;
        int j = jbase + jl;
        float c = (j != i_local) ? dist : 3.0e38f;
        bool m[10];
#pragma unroll
        for (int k = 0; k < 10; ++k) m[k] = c < bd[k];
#pragma unroll
        for (int k = 9; k >= 1; --k) {
            int t = m[k-1] ? bi[k-1] : j;
            bi[k] = m[k] ? t : bi[k];
            bd[k] = __builtin_amdgcn_fmed3f(c, bd[k-1], bd[k]);
        }
        bi[0] = m[0] ? j : bi[0];
        bd[0] = fminf(c, bd[0]);
    }
    size_t base = ((size_t)(b * NPTS + i_local) * JCH + jc) * 10;
#pragma unroll
    for (int r = 0; r < 10; ++r) { pd[base + r] = bd[r]; pi_[base + r] = (ushort_t)bi[r]; }
}

// ---------------- KNN phase B: lane-parallel merge, 8 lanes per node ----------------
__global__ __launch_bounds__(256) void knn_merge(const float* __restrict__ pd,
                                                 const ushort_t* __restrict__ pi_,
                                                 int* __restrict__ nbors,
                                                 int* __restrict__ cnt) {
    int tid = blockIdx.x * 256 + threadIdx.x;     // 0..131071
    int node = tid >> 3;                          // 0..16383
    int sub  = tid & 7;                           // list index (jc)
    int b = node >> 10, i = node & 1023;
    int lane = threadIdx.x & 63;

    size_t base = ((size_t)node * JCH + sub) * 10;
    float d[11]; int id[10];
    {
        const float2* dp = (const float2*)(pd + base);
        const unsigned int* ip = (const unsigned int*)(pi_ + base);
#pragma unroll
        for (int q = 0; q < 5; ++q) {
            float2 dv = dp[q];
            unsigned int iv = ip[q];
            d[2*q] = dv.x; d[2*q+1] = dv.y;
            id[2*q] = (int)(iv & 0xffffu); id[2*q+1] = (int)(iv >> 16);
        }
        d[10] = 3.0e38f;
    }

    int res[10];
#pragma unroll
    for (int r = 0; r < 10; ++r) {
        float hd = d[0]; int hl = sub;
#pragma unroll
        for (int mk = 1; mk <= 4; mk <<= 1) {
            float od = __shfl_xor(hd, mk, 64);
            int   ol = __shfl_xor(hl, mk, 64);
            bool take = (od < hd) || (od == hd && ol < hl);
            hd = take ? od : hd;
            hl = take ? ol : hl;
        }
        int src = (lane & 56) | hl;
        res[r] = __shfl(id[0], src, 64);
        bool win = (sub == hl);
#pragma unroll
        for (int k = 0; k < 9; ++k) {
            d[k]  = win ? d[k+1]  : d[k];
            id[k] = win ? id[k+1] : id[k];
        }
        d[9] = win ? d[10] : d[9];
    }

    if (sub == 0) {
        int gi = b * NPTS + i;
#pragma unroll
        for (int r = 0; r < 10; ++r) {
            int gdst = b * NPTS + uclamp(res[r], NPTS - 1);
            nbors[gi * KNN + r] = gdst;
            atomicAdd(&cnt[gdst], 1);
        }
    }
}

// ---------------- reverse-CSR build ----------------
__global__ __launch_bounds__(256) void scan_kernel(const int* __restrict__ cnt,
                                                   int* __restrict__ rs) {
    __shared__ int part[256];
    int t = threadIdx.x;
    int base = t << 6;
    int4 v[16];
    const int4* cp = (const int4*)(cnt + base);
#pragma unroll
    for (int q = 0; q < 16; ++q) v[q] = cp[q];
    int s = 0;
#pragma unroll
    for (int q = 0; q < 16; ++q) s += v[q].x + v[q].y + v[q].z + v[q].w;
    part[t] = s;
    __syncthreads();
    for (int off = 1; off < 256; off <<= 1) {
        int vv = (t >= off) ? part[t - off] : 0;
        __syncthreads();
        part[t] += vv;
        __syncthreads();
    }
    int run = part[t] - s;
    int4* rp = (int4*)(rs + base);
#pragma unroll
    for (int q = 0; q < 16; ++q) {
        int4 o;
        o.x = run; run += v[q].x;
        o.y = run; run += v[q].y;
        o.z = run; run += v[q].z;
        o.w = run; run += v[q].w;
        rp[q] = o;
    }
    if (t == 255) rs[NODES] = run;
}

__global__ __launch_bounds__(256) void fill_kernel(const int* __restrict__ nbors,
                                                   const int* __restrict__ rs,
                                                   int* __restrict__ cur,
                                                   int* __restrict__ esrc) {
    int e = blockIdx.x * 256 + threadIdx.x;
    if (e < EDGES) {
        int dst = uclamp(nbors[e], NODES - 1);
        int src = e / 10;
        int pos = atomicAdd(&cur[dst], 1);
        esrc[uclamp(rs[dst] + pos, EDGES - 1)] = src;
    }
}

// ---------------- layer-0 GEMM (f32 vector, K=16, N=128) + fused neighbor-agg -------
// Fold-in: cast layer-1..3 weights f32 -> bf16 (229376 elems, grid-stride) at start
// (wb is first read 2 dispatches later by gemm2 L1 -> stream-ordered safe).
__global__ __launch_bounds__(256) void gemm_layer0(const float* __restrict__ A1,
                                                   const int* __restrict__ rs,
                                                   const int* __restrict__ esrc,
                                                   const float* __restrict__ W1,
                                                   const float* __restrict__ W2,
                                                   const float* __restrict__ bias,
                                                   ushort_t* __restrict__ Out,
                                                   const float* __restrict__ s0,
                                                   const float* __restrict__ s1,
                                                   const float* __restrict__ s2,
                                                   const float* __restrict__ s3,
                                                   const float* __restrict__ s4,
                                                   const float* __restrict__ s5,
                                                   ushort_t* __restrict__ wbdst) {
    __shared__ float As1[16 * 64], As2[16 * 64], Bs1[16 * 128], Bs2[16 * 128];
    int tid = threadIdx.x;
    int m0 = blockIdx.x * 64;

    // fold-in: weight cast (grid 256x256 = 65536 threads, 229376 elems -> <=4/thread)
    for (int t = blockIdx.x * 256 + tid; t < 229376; t += 65536) {
        const float* s; int off;
        if      (t <  32768) { s = s0; off = 0; }
        else if (t <  65536) { s = s1; off = 32768; }
        else if (t < 131072) { s = s2; off = 65536; }
        else if (t < 196608) { s = s3; off = 131072; }
        else if (t < 212992) { s = s4; off = 196608; }
        else                 { s = s5; off = 212992; }
        wbdst[t] = f2bf(s[t - off]);
    }

    {   // stage x^T for this block's 64 rows
        int lr = tid >> 2, lc = (tid & 3) << 2;
        float4 a = *(const float4*)(A1 + (size_t)(m0 + lr) * 16 + lc);
        As1[(lc + 0) * 64 + lr] = a.x; As1[(lc + 1) * 64 + lr] = a.y;
        As1[(lc + 2) * 64 + lr] = a.z; As1[(lc + 3) * 64 + lr] = a.w;
    }
    {   // stage both weight matrices (128 x 16) transposed
        int wr = tid >> 1, wc = (tid & 1) << 3;
        float4 wa = *(const float4*)(W1 + (size_t)wr * 16 + wc);
        float4 wb = *(const float4*)(W1 + (size_t)wr * 16 + wc + 4);
        Bs1[(wc + 0) * 128 + wr] = wa.x; Bs1[(wc + 1) * 128 + wr] = wa.y;
        Bs1[(wc + 2) * 128 + wr] = wa.z; Bs1[(wc + 3) * 128 + wr] = wa.w;
        Bs1[(wc + 4) * 128 + wr] = wb.x; Bs1[(wc + 5) * 128 + wr] = wb.y;
        Bs1[(wc + 6) * 128 + wr] = wb.z; Bs1[(wc + 7) * 128 + wr] = wb.w;
        float4 va = *(const float4*)(W2 + (size_t)wr * 16 + wc);
        float4 vb = *(const float4*)(W2 + (size_t)wr * 16 + wc + 4);
        Bs2[(wc + 0) * 128 + wr] = va.x; Bs2[(wc + 1) * 128 + wr] = va.y;
        Bs2[(wc + 2) * 128 + wr] = va.z; Bs2[(wc + 3) * 128 + wr] = va.w;
        Bs2[(wc + 4) * 128 + wr] = vb.x; Bs2[(wc + 5) * 128 + wr] = vb.y;
        Bs2[(wc + 6) * 128 + wr] = vb.z; Bs2[(wc + 7) * 128 + wr] = vb.w;
    }
    {   // fused agg: 4 threads/row, 4 channels each; index-preload (cap 16)
        int r = tid >> 2;
        int c4 = (tid & 3) << 2;
        int n = m0 + r;
        int e1 = uclamp(rs[n + 1], EDGES);
        int e0 = uclamp(rs[n], e1);
        int m = e1 - e0;
        int mm = m < 16 ? m : 16;
        int idx[16];
#pragma unroll
        for (int t = 0; t < 16; ++t)
            idx[t] = (t < mm) ? uclamp(esrc[e0 + t], NODES - 1) : 0;
        float4 acc4 = {0.f, 0.f, 0.f, 0.f};
#pragma unroll
        for (int t = 0; t < 16; ++t) {
            if (t < mm) {
                float4 v = *(const float4*)(A1 + (size_t)idx[t] * 16 + c4);
                acc4.x += v.x; acc4.y += v.y; acc4.z += v.z; acc4.w += v.w;
            }
        }
        for (int e = e0 + 16; e < e1; ++e) {
            int s = uclamp(esrc[e], NODES - 1);
            float4 v = *(const float4*)(A1 + (size_t)s * 16 + c4);
            acc4.x += v.x; acc4.y += v.y; acc4.z += v.z; acc4.w += v.w;
        }
        As2[(c4 + 0) * 64 + r] = acc4.x; As2[(c4 + 1) * 64 + r] = acc4.y;
        As2[(c4 + 2) * 64 + r] = acc4.z; As2[(c4 + 3) * 64 + r] = acc4.w;
    }
    __syncthreads();

    float acc[4][8] = {};
    int ty = tid >> 4;     // 16 row-groups of 4 -> 64 rows
    int tx = tid & 15;     // 16 col-groups of 8 -> 128 cols
#pragma unroll
    for (int k = 0; k < 16; ++k) {
        float4 a1 = *(const float4*)(As1 + k * 64 + (ty << 2));
        float4 a2 = *(const float4*)(As2 + k * 64 + (ty << 2));
        float4 b1l = *(const float4*)(Bs1 + k * 128 + (tx << 3));
        float4 b1h = *(const float4*)(Bs1 + k * 128 + (tx << 3) + 4);
        float4 b2l = *(const float4*)(Bs2 + k * 128 + (tx << 3));
        float4 b2h = *(const float4*)(Bs2 + k * 128 + (tx << 3) + 4);
        float av1[4] = {a1.x, a1.y, a1.z, a1.w};
        float av2[4] = {a2.x, a2.y, a2.z, a2.w};
        float bv1[8] = {b1l.x, b1l.y, b1l.z, b1l.w, b1h.x, b1h.y, b1h.z, b1h.w};
        float bv2[8] = {b2l.x, b2l.y, b2l.z, b2l.w, b2h.x, b2h.y, b2h.z, b2h.w};
#pragma unroll
        for (int u = 0; u < 4; ++u)
#pragma unroll
            for (int v = 0; v < 8; ++v)
                acc[u][v] += av1[u] * bv1[v] + av2[u] * bv2[v];
    }
    float bv[8];
#pragma unroll
    for (int v = 0; v < 8; ++v) bv[v] = bias[(tx << 3) + v];
#pragma unroll
    for (int u = 0; u < 4; ++u) {
        int m = m0 + (ty << 2) + u;
        ushort4 o0, o1;
        o0.x = f2bf(fmaxf(acc[u][0] + bv[0], 0.f));
        o0.y = f2bf(fmaxf(acc[u][1] + bv[1], 0.f));
        o0.z = f2bf(fmaxf(acc[u][2] + bv[2], 0.f));
        o0.w = f2bf(fmaxf(acc[u][3] + bv[3], 0.f));
        o1.x = f2bf(fmaxf(acc[u][4] + bv[4], 0.f));
        o1.y = f2bf(fmaxf(acc[u][5] + bv[5], 0.f));
        o1.z = f2bf(fmaxf(acc[u][6] + bv[6], 0.f));
        o1.w = f2bf(fmaxf(acc[u][7] + bv[7], 0.f));
        *(ushort4*)(Out + (size_t)m * 128 + (tx << 3)) = o0;
        *(ushort4*)(Out + (size_t)m * 128 + (tx << 3) + 4) = o1;
    }
}

// ---------------- aggregation bf16 (layers 1-2), 2-way edge split + index preload ---
__global__ __launch_bounds__(256) void agg_bf16(const ushort_t* __restrict__ hin,
                                                ushort_t* __restrict__ agg,
                                                const int* __restrict__ rs,
                                                const int* __restrict__ esrc,
                                                int din, int sh) {
    int gid = blockIdx.x * 256 + threadIdx.x;
    int n = gid >> sh;
    int sub = gid & ((1 << sh) - 1);
    int half = 1 << (sh - 1);
    int c = (sub & (half - 1)) << 3;
    int par = sub >> (sh - 1);
    int e1 = uclamp(rs[n + 1], EDGES);
    int e0 = uclamp(rs[n], e1);
    int ebase = e0 + par;
    int m = (e1 > ebase) ? ((e1 - ebase + 1) >> 1) : 0;
    int mm = m < 12 ? m : 12;
    int idx[12];
#pragma unroll
    for (int t = 0; t < 12; ++t)
        idx[t] = (t < mm) ? uclamp(esrc[ebase + 2 * t], NODES - 1) : 0;
    float a[8] = {0.f,0.f,0.f,0.f,0.f,0.f,0.f,0.f};
#pragma unroll
    for (int t = 0; t < 12; ++t) {
        if (t < mm) {
            u16x8 v = *(const u16x8*)(hin + (size_t)idx[t] * din + c);
#pragma unroll
            for (int k = 0; k < 8; ++k) a[k] += bf2f(v[k]);
        }
    }
    for (int e = ebase + 24; e < e1; e += 2) {
        int s = uclamp(esrc[e], NODES - 1);
        u16x8 v = *(const u16x8*)(hin + (size_t)s * din + c);
#pragma unroll
        for (int k = 0; k < 8; ++k) a[k] += bf2f(v[k]);
    }
#pragma unroll
    for (int k = 0; k < 8; ++k) a[k] += __shfl_xor(a[k], half, 64);
    if (par == 0) {
        u16x8 o;
#pragma unroll
        for (int k = 0; k < 8; ++k) o[k] = f2bf(a[k]);
        *(u16x8*)(agg + (size_t)n * din + c) = o;
    }
}

// ---------------- MFMA dual-GEMM with LDS-staged weights (layers 1-2) ----------------
template<int KD>
__global__ __launch_bounds__(256) void gemm2(const ushort_t* __restrict__ A1,
                                             const ushort_t* __restrict__ A2,
                                             const ushort_t* __restrict__ W1,
                                             const ushort_t* __restrict__ W2,
                                             const float* __restrict__ bias,
                                             ushort_t* __restrict__ outp) {
    __shared__ ushort_t Ws1[64 * KD], Ws2[64 * KD];
    int tid = threadIdx.x;
    int m0 = blockIdx.y * 64;
    int n0 = blockIdx.x * 64;

    {   // stage weight tiles: coalesced global, swizzled LDS
        constexpr int VPM = 64 * KD / 8;
#pragma unroll
        for (int j = 0; j < VPM / 256; ++j) {
            int vi = j * 256 + tid;
            int row = vi / (KD / 8);
            int ch  = (vi % (KD / 8)) * 8;
            u16x8 w1 = *(const u16x8*)(W1 + (size_t)(n0 + row) * KD + ch);
            u16x8 w2 = *(const u16x8*)(W2 + (size_t)(n0 + row) * KD + ch);
            unsigned byte = ((unsigned)(row * KD + ch) * 2u)
                          ^ (((unsigned)(row & 7)) << 4);
            *(u16x8*)((char*)Ws1 + byte) = w1;
            *(u16x8*)((char*)Ws2 + byte) = w2;
        }
    }
    __syncthreads();

    int wave = tid >> 6, lane = tid & 63;
    int quad = lane >> 4, l16 = lane & 15;
    int ms = m0 + wave * 16;

    f32x4 acc[4] = {};
    const ushort_t* a1p = A1 + (size_t)(ms + l16) * KD + quad * 8;
    const ushort_t* a2p = A2 + (size_t)(ms + l16) * KD + quad * 8;

#pragma unroll
    for (int k0 = 0; k0 < KD; k0 += 32) {
        bf16x8 a1 = *(const bf16x8*)(a1p + k0);
        bf16x8 a2 = *(const bf16x8*)(a2p + k0);
#pragma unroll
        for (int nt = 0; nt < 4; ++nt) {
            int row = nt * 16 + l16;
            unsigned byte = ((unsigned)(row * KD + quad * 8 + k0) * 2u)
                          ^ (((unsigned)(row & 7)) << 4);
            bf16x8 u = *(const bf16x8*)((const char*)Ws1 + byte);
            bf16x8 v = *(const bf16x8*)((const char*)Ws2 + byte);
            acc[nt] = __builtin_amdgcn_mfma_f32_16x16x32_bf16(a1, u, acc[nt], 0, 0, 0);
            acc[nt] = __builtin_amdgcn_mfma_f32_16x16x32_bf16(a2, v, acc[nt], 0, 0, 0);
        }
    }
#pragma unroll
    for (int nt = 0; nt < 4; ++nt) {
        int n = n0 + nt * 16 + l16;
        float bb = bias[n];
#pragma unroll
        for (int r = 0; r < 4; ++r) {
            float v = fmaxf(acc[nt][r] + bb, 0.f);
            int m = ms + quad * 4 + r;
            outp[(size_t)m * 256 + n] = f2bf(v);
        }
    }
}

// ---------------- layer-3 GEMM: shared-A dual out, LDS-staged weights ----------------
__global__ __launch_bounds__(256) void gemm_l3(const ushort_t* __restrict__ A,
                                               const ushort_t* __restrict__ Wroot,
                                               const ushort_t* __restrict__ Wrel,
                                               float* __restrict__ Q3,
                                               float* __restrict__ P3) {
    constexpr int KD = 256;
    __shared__ ushort_t Ws1[64 * KD], Ws2[64 * KD];   // 64 KB
    int tid = threadIdx.x;
    int ms = blockIdx.y * 64 + (tid >> 6) * 16;

    {
        constexpr int VPM = 64 * KD / 8;
#pragma unroll
        for (int j = 0; j < VPM / 256; ++j) {
            int vi = j * 256 + tid;
            int row = vi / (KD / 8);
            int ch  = (vi % (KD / 8)) * 8;
            u16x8 w1 = *(const u16x8*)(Wroot + (size_t)row * KD + ch);
            u16x8 w2 = *(const u16x8*)(Wrel + (size_t)row * KD + ch);
            unsigned byte = ((unsigned)(row * KD + ch) * 2u)
                          ^ (((unsigned)(row & 7)) << 4);
            *(u16x8*)((char*)Ws1 + byte) = w1;
            *(u16x8*)((char*)Ws2 + byte) = w2;
        }
    }
    __syncthreads();

    int lane = tid & 63;
    int quad = lane >> 4, l16 = lane & 15;

    f32x4 accQ[4] = {};
    f32x4 accP[4] = {};
    const ushort_t* ap = A + (size_t)(ms + l16) * KD + quad * 8;

#pragma unroll
    for (int k0 = 0; k0 < KD; k0 += 32) {
        bf16x8 a = *(const bf16x8*)(ap + k0);
#pragma unroll
        for (int nt = 0; nt < 4; ++nt) {
            int row = nt * 16 + l16;
            unsigned byte = ((unsigned)(row * KD + quad * 8 + k0) * 2u)
                          ^ (((unsigned)(row & 7)) << 4);
            bf16x8 u = *(const bf16x8*)((const char*)Ws1 + byte);
            bf16x8 v = *(const bf16x8*)((const char*)Ws2 + byte);
            accQ[nt] = __builtin_amdgcn_mfma_f32_16x16x32_bf16(a, u, accQ[nt], 0, 0, 0);
            accP[nt] = __builtin_amdgcn_mfma_f32_16x16x32_bf16(a, v, accP[nt], 0, 0, 0);
        }
    }
#pragma unroll
    for (int nt = 0; nt < 4; ++nt) {
        int n = nt * 16 + l16;
#pragma unroll
        for (int r = 0; r < 4; ++r) {
            int m = ms + quad * 4 + r;
            Q3[(size_t)m * 64 + n] = accQ[nt][r];
            P3[(size_t)m * 64 + n] = accP[nt][r];
        }
    }
}

// ---------------- layer-3 aggregate + bias + hi/lo split (2-way split + preload) ----
__global__ __launch_bounds__(256) void agg_final(const float* __restrict__ P3,
                                                 const float* __restrict__ Q3,
                                                 const float* __restrict__ bias,
                                                 const int* __restrict__ rs,
                                                 const int* __restrict__ esrc,
                                                 ushort_t* __restrict__ h4hi,
                                                 ushort_t* __restrict__ h4lo) {
    int gid = blockIdx.x * 256 + threadIdx.x;     // 0..524287
    int n = gid >> 5;
    int sub = gid & 31;
    int c = (sub & 15) << 2;
    int par = sub >> 4;
    int e1 = uclamp(rs[n + 1], EDGES);
    int e0 = uclamp(rs[n], e1);
    int ebase = e0 + par;
    int m = (e1 > ebase) ? ((e1 - ebase + 1) >> 1) : 0;
    int mm = m < 8 ? m : 8;
    int idx[8];
#pragma unroll
    for (int t = 0; t < 8; ++t)
        idx[t] = (t < mm) ? uclamp(esrc[ebase + 2 * t], NODES - 1) : 0;
    float4 acc = {0.f, 0.f, 0.f, 0.f};
#pragma unroll
    for (int t = 0; t < 8; ++t) {
        if (t < mm) {
            float4 v = *(const float4*)(P3 + (size_t)idx[t] * 64 + c);
            acc.x += v.x; acc.y += v.y; acc.z += v.z; acc.w += v.w;
        }
    }
    for (int e = ebase + 16; e < e1; e += 2) {
        int s = uclamp(esrc[e], NODES - 1);
        float4 v = *(const float4*)(P3 + (size_t)s * 64 + c);
        acc.x += v.x; acc.y += v.y; acc.z += v.z; acc.w += v.w;
    }
    acc.x += __shfl_xor(acc.x, 16, 64);
    acc.y += __shfl_xor(acc.y, 16, 64);
    acc.z += __shfl_xor(acc.z, 16, 64);
    acc.w += __shfl_xor(acc.w, 16, 64);
    if (par == 0) {
        float4 q = *(const float4*)(Q3 + (size_t)n * 64 + c);
        float4 bb = *(const float4*)(bias + c);
        float v0 = acc.x + q.x + bb.x;
        float v1 = acc.y + q.y + bb.y;
        float v2 = acc.z + q.z + bb.z;
        float v3 = acc.w + q.w + bb.w;
        ushort4 hi, lo;
        hi.x = f2bf(v0); lo.x = f2bf(v0 - bf2f(hi.x));
        hi.y = f2bf(v1); lo.y = f2bf(v1 - bf2f(hi.y));
        hi.z = f2bf(v2); lo.z = f2bf(v2 - bf2f(hi.z));
        hi.w = f2bf(v3); lo.w = f2bf(v3 - bf2f(hi.w));
        *(ushort4*)(h4hi + (size_t)n * 64 + c) = hi;
        *(ushort4*)(h4lo + (size_t)n * 64 + c) = lo;
    }
}

// ---------------- final Gram via split-bf16 MFMA: D = H·H^T, f32 out ----------------
// 128x128 output tile per block (grid 8x8x16 = 1024 blocks).
__global__ __launch_bounds__(256) void final_mfma(const ushort_t* __restrict__ Hhi,
                                                  const ushort_t* __restrict__ Hlo,
                                                  float* __restrict__ out) {
    int tid = threadIdx.x;
    int wave = tid >> 6, lane = tid & 63;
    int quad = lane >> 4, l16 = lane & 15;
    int bz = blockIdx.z;
    int m0 = blockIdx.x * 128;
    int n0 = blockIdx.y * 128 + wave * 32;
    const ushort_t* Hbh = Hhi + (size_t)bz * NPTS * 64;
    const ushort_t* Hbl = Hlo + (size_t)bz * NPTS * 64;

    f32x4 acc[2][8] = {};
    const ushort_t* aph = Hbh + (size_t)(n0 + l16) * 64 + quad * 8;
    const ushort_t* apl = Hbl + (size_t)(n0 + l16) * 64 + quad * 8;
    const ushort_t* bph = Hbh + (size_t)(m0 + l16) * 64 + quad * 8;
    const ushort_t* bpl = Hbl + (size_t)(m0 + l16) * 64 + quad * 8;

#pragma unroll
    for (int k0 = 0; k0 < 64; k0 += 32) {
        bf16x8 bh[8], bl[8];
#pragma unroll
        for (int mt = 0; mt < 8; ++mt) {
            bh[mt] = *(const bf16x8*)(bph + (size_t)mt * 16 * 64 + k0);
            bl[mt] = *(const bf16x8*)(bpl + (size_t)mt * 16 * 64 + k0);
        }
#pragma unroll
        for (int nt = 0; nt < 2; ++nt) {
            bf16x8 ah = *(const bf16x8*)(aph + (size_t)nt * 16 * 64 + k0);
            bf16x8 al = *(const bf16x8*)(apl + (size_t)nt * 16 * 64 + k0);
#pragma unroll
            for (int mt = 0; mt < 8; ++mt) {
                acc[nt][mt] = __builtin_amdgcn_mfma_f32_16x16x32_bf16(ah, bh[mt], acc[nt][mt], 0, 0, 0);
                acc[nt][mt] = __builtin_amdgcn_mfma_f32_16x16x32_bf16(ah, bl[mt], acc[nt][mt], 0, 0, 0);
                acc[nt][mt] = __builtin_amdgcn_mfma_f32_16x16x32_bf16(al, bh[mt], acc[nt][mt], 0, 0, 0);
            }
        }
    }
#pragma unroll
    for (int nt = 0; nt < 2; ++nt)
#pragma unroll
        for (int mt = 0; mt < 8; ++mt)
#pragma unroll
            for (int r = 0; r < 4; ++r) {
                int n = n0 + nt * 16 + quad * 4 + r;
                int m = m0 + mt * 16 + l16;
                out[((size_t)(bz * NPTS + n)) * NPTS + m] = acc[nt][mt][r];
            }
}

// ---------------- launch ----------------
extern "C" void kernel_launch(void* const* d_in, const int* in_sizes, int n_in,
                              void* d_out, int out_size, void* d_ws, size_t ws_size,
                              hipStream_t stream) {
    const float* x = (const float*)d_in[0];
    const float* W[12];
    for (int i = 0; i < 12; ++i) W[i] = (const float*)d_in[1 + i];
    float* out = (float*)d_out;

    // d_ws (~5.5 MB): h4 hi/lo + graph structs
    char* w = (char*)d_ws;
    ushort_t* h4hi = (ushort_t*)w; w += (size_t)NODES * 64 * 2;     // 2 MB
    ushort_t* h4lo = (ushort_t*)w; w += (size_t)NODES * 64 * 2;     // 2 MB
    int* nbors  = (int*)w;    w += (size_t)EDGES * 4;               // 640 KB
    int* cnt    = (int*)w;    w += (size_t)NODES * 4;               // 64 KB
    int* cur    = (int*)w;    w += (size_t)NODES * 4;               // 64 KB (contiguous after cnt)
    int* rs     = (int*)w;    w += (size_t)(NODES + 1) * 4 + 12;    // 64 KB
    int* esrc   = (int*)w;    w += (size_t)EDGES * 4;               // 640 KB

    // scratch inside d_out (64 MB, fully overwritten by final_mfma).
    char* ob = (char*)d_out;
    ushort_t* wb    = (ushort_t*)(ob + 0);                   // 448 KB bf16 weights
    float*    pd    = (float*)   (ob + (size_t) 1u*1048576); // 5 MiB [node][jc(8)][10] f32
    ushort_t* pi_   = (ushort_t*)(ob + (size_t) 6u*1048576); // 2.5 MiB
    ushort_t* h1b   = (ushort_t*)(ob + (size_t) 1u*1048576); // 4 MB  (aliases pd)
    ushort_t* h2b   = (ushort_t*)(ob + (size_t)13u*1048576); // 8 MB
    ushort_t* h3b   = (ushort_t*)(ob + (size_t)21u*1048576); // 8 MB
    float*    P3    = (float*)   (ob + (size_t)29u*1048576); // 4 MB f32 (h3.Wrel^T)
    float*    Q3    = (float*)   (ob + (size_t)33u*1048576); // 4 MB f32 (h3.Wroot^T)
    ushort_t* aggb  = (ushort_t*)(ob + (size_t)37u*1048576); // 8 MB bf16 agg

    knn_partial<<<dim3(JCH, 8, BATCH), 128, 0, stream>>>(x, pd, pi_, cnt);
    knn_merge<<<512, 256, 0, stream>>>(pd, pi_, nbors, cnt);   // fused in-degree count
    scan_kernel<<<1, 256, 0, stream>>>(cnt, rs);
    fill_kernel<<<EDGES / 256, 256, 0, stream>>>(nbors, rs, cur, esrc);

    // layer 0: K=16, N=128, f32 compute, fused neighbor-agg + weight-cast, bf16 out
    gemm_layer0<<<256, 256, 0, stream>>>(x, rs, esrc, W[0], W[1], W[2], h1b,
                                         W[3], W[4], W[6], W[7], W[9], W[10], wb);
    // layer 1: K=128, N=256  (agg: 32 thr/node -> sh=5; gemm: LDS weights)
    agg_bf16<<<NODES * 32 / 256, 256, 0, stream>>>(h1b, aggb, rs, esrc, 128, 5);
    gemm2<128><<<dim3(4, 256), 256, 0, stream>>>(h1b, aggb, wb, wb + 32768, W[5], h2b);
    // layer 2: K=256, N=256  (agg: 64 thr/node -> sh=6)
    agg_bf16<<<NODES * 64 / 256, 256, 0, stream>>>(h2b, aggb, rs, esrc, 256, 6);
    gemm2<256><<<dim3(4, 256), 256, 0, stream>>>(h2b, aggb, wb + 65536, wb + 131072,
                                                 W[8], h3b);
    // layer 3: project first (LDS weights), then aggregate 64-dim rows
    gemm_l3<<<dim3(1, 256), 256, 0, stream>>>(h3b, wb + 196608, wb + 212992, Q3, P3);
    agg_final<<<NODES * 32 / 256, 256, 0, stream>>>(P3, Q3, W[11], rs, esrc, h4hi, h4lo);

    final_mfma<<<dim3(8, 8, 16), 256, 0, stream>>>(h4hi, h4lo, out);
}